// Round 1
// baseline (1668.234 us; speedup 1.0000x reference)
//
#include <hip/hip_runtime.h>
#include <hip/hip_bf16.h>
#include <math.h>

#define NNODES  50000
#define NEDGES  200000
#define NTOT    250000      // E + N self loops
#define EMB     300
#define LDH     304         // padded row stride for h / mh
#define MPAD    50048       // 782 * 64 (GEMM M padding)
#define NLAYERS 5

struct EdgeRec { int r; float c0, c1; };

// ---------------- node init: h = x_emb[x_type] + x_feat @ x_weight ----------------
__global__ __launch_bounds__(320) void k_init(const int* __restrict__ xt,
                                              const float* __restrict__ xf,
                                              const float* __restrict__ xemb,
                                              const float* __restrict__ xw,
                                              float* __restrict__ h) {
    int n = blockIdx.x;
    int j = threadIdx.x;
    __shared__ float fs[16];
    if (j < 16) fs[j] = xf[n * 16 + j];
    __syncthreads();
    if (j < LDH) {
        float v = 0.f;
        if (j < 300) {
            v = xemb[xt[n] * 300 + j];
            #pragma unroll
            for (int k = 0; k < 16; ++k) v += fs[k] * xw[k * 300 + j];
        }
        h[(long)n * LDH + j] = v;
    }
}

// ---------------- CSR build ----------------
__global__ void k_count(const int* __restrict__ ei, int* __restrict__ cnt) {
    int e = blockIdx.x * blockDim.x + threadIdx.x;
    if (e >= NTOT) return;
    int c = (e < NEDGES) ? ei[NEDGES + e] : (e - NEDGES);
    atomicAdd(&cnt[c], 1);
}

__global__ __launch_bounds__(1024) void k_scan(const int* __restrict__ cnt, int* __restrict__ off) {
    __shared__ int buf[1024];
    __shared__ int carry;
    int tid = threadIdx.x;
    if (tid == 0) carry = 0;
    __syncthreads();
    for (int base = 0; base < NNODES; base += 1024) {
        int v = (base + tid < NNODES) ? cnt[base + tid] : 0;
        buf[tid] = v;
        __syncthreads();
        for (int s = 1; s < 1024; s <<= 1) {
            int t = (tid >= s) ? buf[tid - s] : 0;
            __syncthreads();
            buf[tid] += t;
            __syncthreads();
        }
        if (base + tid < NNODES) off[base + tid] = carry + buf[tid] - v;
        __syncthreads();
        if (tid == 0) carry += buf[1023];
        __syncthreads();
    }
    if (tid == 0) off[NNODES] = carry;
}

__global__ void k_fill(const int* __restrict__ ei, const float* __restrict__ ea,
                       const int* __restrict__ off, int* __restrict__ cur,
                       EdgeRec* __restrict__ pack) {
    int e = blockIdx.x * blockDim.x + threadIdx.x;
    if (e >= NTOT) return;
    int r, c; float c0, c1;
    if (e < NEDGES) { r = ei[e]; c = ei[NEDGES + e]; c0 = ea[2 * e]; c1 = ea[2 * e + 1]; }
    else            { r = c = e - NEDGES; c0 = 0.f; c1 = 4.f; }
    int p = atomicAdd(&cur[c], 1);
    EdgeRec rec; rec.r = r; rec.c0 = c0; rec.c1 = c1;
    pack[off[c] + p] = rec;
}

// ---------------- per-layer precompute: u0 = W@ew1[0], u1 = W@ew1[1], bias, BN scale/shift ----------------
__global__ __launch_bounds__(320) void k_prep(const float* __restrict__ W, const float* __restrict__ ew,
                                              const float* __restrict__ mb, const float* __restrict__ g,
                                              const float* __restrict__ bb, const float* __restrict__ rm,
                                              const float* __restrict__ rv, float* __restrict__ prm) {
    int j = threadIdx.x;
    if (j >= 300) return;
    float a0 = 0.f, a1 = 0.f;
    for (int k = 0; k < 300; ++k) {
        float w = W[j * 300 + k];
        a0 += w * ew[k];
        a1 += w * ew[300 + k];
    }
    prm[j] = a0;
    prm[304 + j] = a1;
    prm[608 + j] = mb[j];
    float sc = g[j] * rsqrtf(rv[j] + 1e-5f);
    prm[912 + j] = sc;
    prm[1216 + j] = bb[j] - rm[j] * sc;
}

// ---------------- SGEMM: C[M,300] = A[M,300] @ B[300,300]^T (both K-contiguous) ----------------
__global__ __launch_bounds__(256) void k_gemm(const float* __restrict__ A, const float* __restrict__ B,
                                              float* __restrict__ C) {
    __shared__ float As[16][68];
    __shared__ float Bs[16][68];
    int tid = threadIdx.x;
    int row0 = blockIdx.x * 64, col0 = blockIdx.y * 64;
    int tx = tid & 15, ty = tid >> 4;
    float acc[4][4];
    #pragma unroll
    for (int i = 0; i < 4; ++i)
        #pragma unroll
        for (int j = 0; j < 4; ++j) acc[i][j] = 0.f;

    for (int k0 = 0; k0 < LDH; k0 += 16) {
        #pragma unroll
        for (int t0 = 0; t0 < 4; ++t0) {
            int t = tid + t0 * 256;
            int k = t & 15, m = t >> 4;
            As[k][m] = A[(long)(row0 + m) * LDH + k0 + k];   // pad cols of h are 0
            int gn = col0 + m, gk = k0 + k;
            Bs[k][m] = (gn < 300 && gk < 300) ? B[gn * 300 + gk] : 0.f;
        }
        __syncthreads();
        #pragma unroll
        for (int k = 0; k < 16; ++k) {
            float a[4], b[4];
            #pragma unroll
            for (int i = 0; i < 4; ++i) { a[i] = As[k][ty * 4 + i]; b[i] = Bs[k][tx * 4 + i]; }
            #pragma unroll
            for (int i = 0; i < 4; ++i)
                #pragma unroll
                for (int j = 0; j < 4; ++j) acc[i][j] += a[i] * b[j];
        }
        __syncthreads();
    }
    #pragma unroll
    for (int i = 0; i < 4; ++i) {
        long gr = row0 + ty * 4 + i;
        #pragma unroll
        for (int j = 0; j < 4; ++j) {
            int gc = col0 + tx * 4 + j;
            if (gc < LDH) C[gr * LDH + gc] = acc[i][j];
        }
    }
}

// ---------------- aggregate: h[n] = BN( sum_{e->n} relu(mh[row_e] + c0*u0 + c1*u1 + b) ), wave per node ----------------
__global__ __launch_bounds__(256) void k_aggr(const float* __restrict__ mh, const EdgeRec* __restrict__ pack,
                                              const int* __restrict__ off, const float* __restrict__ prm,
                                              float* __restrict__ h, int do_relu) {
    int wave = threadIdx.x >> 6;
    int lane = threadIdx.x & 63;
    int n = blockIdx.x * 4 + wave;
    if (n >= NNODES) return;
    float u0v[5], u1v[5], bv[5], scv[5], shv[5], acc[5];
    #pragma unroll
    for (int i = 0; i < 5; ++i) {
        int j = lane + i * 64;
        bool ok = j < 300;
        u0v[i] = ok ? prm[j]        : 0.f;
        u1v[i] = ok ? prm[304 + j]  : 0.f;
        bv[i]  = ok ? prm[608 + j]  : 0.f;
        scv[i] = ok ? prm[912 + j]  : 0.f;
        shv[i] = ok ? prm[1216 + j] : 0.f;
        acc[i] = 0.f;
    }
    int p0 = off[n], p1 = off[n + 1];
    for (int p = p0; p < p1; ++p) {
        EdgeRec rec = pack[p];
        const float* base = mh + (long)rec.r * LDH;
        #pragma unroll
        for (int i = 0; i < 5; ++i) {
            int j = lane + i * 64;
            float v = (j < 300) ? base[j] : 0.f;
            v += rec.c0 * u0v[i] + rec.c1 * u1v[i] + bv[i];
            acc[i] += fmaxf(v, 0.f);
        }
    }
    #pragma unroll
    for (int i = 0; i < 5; ++i) {
        int j = lane + i * 64;
        if (j < LDH) {
            float v = acc[i] * scv[i] + shv[i];
            if (do_relu) v = fmaxf(v, 0.f);
            h[(long)n * LDH + j] = (j < 300) ? v : 0.f;
        }
    }
}

// ---------------- metal branch: mf, Q, qk = Q@wk, metal2 ----------------
__global__ __launch_bounds__(320) void k_metal(const int* __restrict__ mt, const float* __restrict__ mfeat,
                                               const float* __restrict__ me1w, const float* __restrict__ me1b,
                                               const float* __restrict__ me2,
                                               const float* __restrict__ wq, const float* __restrict__ wk,
                                               const float* __restrict__ mlw, const float* __restrict__ mlb,
                                               float* __restrict__ metal2, float* __restrict__ qk) {
    int b = blockIdx.x;
    int tid = threadIdx.x;
    __shared__ float fs[17];
    __shared__ float mf_s[300];
    __shared__ float q_s[256];
    if (tid < 17) fs[tid] = mfeat[b * 17 + tid];
    __syncthreads();
    if (tid < 300) {
        float v = me1b[tid] + me2[mt[b] * 300 + tid];
        #pragma unroll
        for (int k = 0; k < 17; ++k) v += fs[k] * me1w[tid * 17 + k];
        mf_s[tid] = v;
    }
    __syncthreads();
    if (tid < 256) {
        float q = 0.f, m2 = 0.f;
        for (int k = 0; k < 300; ++k) {
            float m = mf_s[k];
            q  += m * wq[tid * 300 + k];
            m2 += m * mlw[tid * 300 + k];
        }
        q_s[tid] = q;
        metal2[b * 256 + tid] = fmaxf(m2 + mlb[tid], 0.f);
    }
    __syncthreads();
    if (tid < 300) {
        float a = 0.f;
        for (int j = 0; j < 256; ++j) a += q_s[j] * wk[j * 300 + tid];
        qk[b * 300 + tid] = a;
    }
}

// ---------------- attention pool: scores -> softmax -> weighted pool + mean pool ----------------
__global__ __launch_bounds__(320) void k_pool(const float* __restrict__ h, const float* __restrict__ qk,
                                              float* __restrict__ wpool, float* __restrict__ mean) {
    int b = blockIdx.x;
    int tid = threadIdx.x;
    int wave = tid >> 6, lane = tid & 63;
    __shared__ float qk_s[300];
    __shared__ float sc[50];
    if (tid < 300) qk_s[tid] = qk[b * 300 + tid];
    __syncthreads();
    for (int k = wave; k < 50; k += 5) {
        const float* hp = h + (long)(b * 50 + k) * LDH;
        float partial = 0.f;
        #pragma unroll
        for (int i = 0; i < 5; ++i) {
            int j = lane + i * 64;
            if (j < 300) partial += hp[j] * qk_s[j];
        }
        #pragma unroll
        for (int s = 32; s > 0; s >>= 1) partial += __shfl_xor(partial, s, 64);
        if (lane == 0) sc[k] = partial * (1.f / 16.f);
    }
    __syncthreads();
    if (tid == 0) {
        float mx = sc[0];
        for (int k = 1; k < 50; ++k) mx = fmaxf(mx, sc[k]);
        float s = 0.f;
        for (int k = 0; k < 50; ++k) { float e = __expf(sc[k] - mx); sc[k] = e; s += e; }
        float inv = 1.f / s;
        for (int k = 0; k < 50; ++k) sc[k] *= inv;
    }
    __syncthreads();
    if (tid < 300) {
        float aw = 0.f, am = 0.f;
        for (int k = 0; k < 50; ++k) {
            float v = h[(long)(b * 50 + k) * LDH + tid];
            aw += sc[k] * v;
            am += v;
        }
        wpool[b * 300 + tid] = aw;
        mean[b * 300 + tid]  = am * (1.f / 50.f);
    }
}

// ---------------- head: att = wpool@wv^T, lig, feature, softplus MLP, out ----------------
__global__ __launch_bounds__(512) void k_head(const float* __restrict__ wpool, const float* __restrict__ mean,
                                              const float* __restrict__ metal2,
                                              const float* __restrict__ wv, const float* __restrict__ lgw,
                                              const float* __restrict__ lgb,
                                              const float* __restrict__ ph1w, const float* __restrict__ ph1b,
                                              const float* __restrict__ ph2w, const float* __restrict__ ph2b,
                                              float* __restrict__ out) {
    int b = blockIdx.x;
    int tid = threadIdx.x;
    __shared__ float wp_s[300], mn_s[300], f_s[256], red[512];
    if (tid < 300) { wp_s[tid] = wpool[b * 300 + tid]; mn_s[tid] = mean[b * 300 + tid]; }
    __syncthreads();
    if (tid < 256) {
        float att = 0.f, lg = 0.f;
        for (int k = 0; k < 300; ++k) {
            att += wp_s[k] * wv[tid * 300 + k];
            lg  += mn_s[k] * lgw[tid * 300 + k];
        }
        lg = fmaxf(lg + lgb[tid], 0.f);
        f_s[tid] = fmaxf(att, 0.f) + metal2[b * 256 + tid] + lg;
    }
    __syncthreads();
    float a = ph1b[tid];
    for (int k = 0; k < 256; ++k) a += f_s[k] * ph1w[tid * 256 + k];
    float sp = fmaxf(a, 0.f) + log1pf(__expf(-fabsf(a)));   // stable softplus
    red[tid] = sp * ph2w[tid];
    __syncthreads();
    for (int s = 256; s > 0; s >>= 1) {
        if (tid < s) red[tid] += red[tid + s];
        __syncthreads();
    }
    if (tid == 0) out[b] = red[0] + ph2b[0];
}

extern "C" void kernel_launch(void* const* d_in, const int* in_sizes, int n_in,
                              void* d_out, int out_size, void* d_ws, size_t ws_size,
                              hipStream_t stream) {
    const int*   x_type   = (const int*)d_in[0];
    const float* x_feat   = (const float*)d_in[1];
    const int*   eindex   = (const int*)d_in[2];
    const float* eattr    = (const float*)d_in[3];
    const int*   mtype    = (const int*)d_in[4];
    const float* mfeat    = (const float*)d_in[5];
    const float* x_emb    = (const float*)d_in[6];
    const float* x_weight = (const float*)d_in[7];
    const float* ew1      = (const float*)d_in[8];
    const float* mlp_w    = (const float*)d_in[9];
    const float* mlp_b    = (const float*)d_in[10];
    const float* bn_g     = (const float*)d_in[11];
    const float* bn_b     = (const float*)d_in[12];
    const float* bn_rm    = (const float*)d_in[13];
    const float* bn_rv    = (const float*)d_in[14];
    const float* me1_w    = (const float*)d_in[15];
    const float* me1_b    = (const float*)d_in[16];
    const float* me2      = (const float*)d_in[17];
    const float* wq       = (const float*)d_in[18];
    const float* wk       = (const float*)d_in[19];
    const float* wv       = (const float*)d_in[20];
    const float* ml_w     = (const float*)d_in[21];
    const float* ml_b     = (const float*)d_in[22];
    const float* lg_w     = (const float*)d_in[23];
    const float* lg_b     = (const float*)d_in[24];
    const float* ph1_w    = (const float*)d_in[25];
    const float* ph1_b    = (const float*)d_in[26];
    const float* ph2_w    = (const float*)d_in[27];
    const float* ph2_b    = (const float*)d_in[28];

    char* ws = (char*)d_ws;
    size_t o = 0;
    auto alloc = [&](size_t bytes) -> void* {
        void* p = ws + o;
        o += (bytes + 255) & ~(size_t)255;
        return p;
    };
    float*   h      = (float*)alloc((size_t)MPAD * LDH * 4);
    float*   mh     = (float*)alloc((size_t)MPAD * LDH * 4);
    int*     cnt    = (int*)alloc((size_t)NNODES * 4);
    int*     offs   = (int*)alloc((size_t)(NNODES + 1) * 4);
    int*     cur    = (int*)alloc((size_t)NNODES * 4);
    EdgeRec* pack   = (EdgeRec*)alloc((size_t)NTOT * sizeof(EdgeRec));
    float*   prm    = (float*)alloc(1520 * 4);
    float*   metal2 = (float*)alloc((size_t)1000 * 256 * 4);
    float*   qk     = (float*)alloc((size_t)1000 * 300 * 4);
    float*   wpool  = (float*)alloc((size_t)1000 * 300 * 4);
    float*   meanp  = (float*)alloc((size_t)1000 * 300 * 4);
    (void)ws_size; (void)in_sizes; (void)n_in; (void)out_size;

    hipMemsetAsync(cnt, 0, (size_t)NNODES * 4, stream);
    hipMemsetAsync(cur, 0, (size_t)NNODES * 4, stream);

    k_init<<<NNODES, 320, 0, stream>>>(x_type, x_feat, x_emb, x_weight, h);
    k_count<<<(NTOT + 255) / 256, 256, 0, stream>>>(eindex, cnt);
    k_scan<<<1, 1024, 0, stream>>>(cnt, offs);
    k_fill<<<(NTOT + 255) / 256, 256, 0, stream>>>(eindex, eattr, offs, cur, pack);

    for (int l = 0; l < NLAYERS; ++l) {
        k_prep<<<1, 320, 0, stream>>>(mlp_w + (size_t)l * 90000, ew1 + l * 600, mlp_b + l * 300,
                                      bn_g + l * 300, bn_b + l * 300, bn_rm + l * 300,
                                      bn_rv + l * 300, prm);
        dim3 g(MPAD / 64, 5);
        k_gemm<<<g, 256, 0, stream>>>(h, mlp_w + (size_t)l * 90000, mh);
        k_aggr<<<(NNODES + 3) / 4, 256, 0, stream>>>(mh, pack, offs, prm, h, (l < NLAYERS - 1) ? 1 : 0);
    }

    k_metal<<<1000, 320, 0, stream>>>(mtype, mfeat, me1_w, me1_b, me2, wq, wk, ml_w, ml_b, metal2, qk);
    k_pool<<<1000, 320, 0, stream>>>(h, qk, wpool, meanp);
    k_head<<<1000, 512, 0, stream>>>(wpool, meanp, metal2, wv, lg_w, lg_b,
                                     ph1_w, ph1_b, ph2_w, ph2_b, (float*)d_out);
}

// Round 2
// 1043.617 us; speedup vs baseline: 1.5985x; 1.5985x over previous
//
#include <hip/hip_runtime.h>
#include <hip/hip_bf16.h>
#include <math.h>

#define NNODES  50000
#define NEDGES  200000
#define NTOT    250000      // E + N self loops
#define EMB     300
#define LDK     320         // padded K stride (bf16 h, bf16 weights, fp32 mh)
#define MPAD    50048       // 391 * 128 (GEMM M padding)
#define NLAYERS 5

struct EdgeRec { int r; float c0, c1; };

typedef __attribute__((ext_vector_type(8))) short short8;
typedef __attribute__((ext_vector_type(4))) float floatx4;

__device__ inline void gll16(const void* g, void* s) {
    __builtin_amdgcn_global_load_lds((const __attribute__((address_space(1))) unsigned*)g,
                                     (__attribute__((address_space(3))) unsigned*)s, 16, 0, 0);
}

// ---------------- weight convert: wb[l][320][320] = bf16(mlp_w[l][300][300]) zero-padded ----------------
__global__ void k_cvt(const float* __restrict__ w, __hip_bfloat16* __restrict__ wb) {
    int idx = blockIdx.x * 256 + threadIdx.x;
    if (idx >= 5 * 320 * 320) return;
    int l = idx / 102400, r = idx % 102400, n = r / 320, k = r % 320;
    float v = (n < 300 && k < 300) ? w[l * 90000 + n * 300 + k] : 0.f;
    wb[idx] = __float2bfloat16(v);
}

// ---------------- node init: h = bf16(x_emb[x_type] + x_feat @ x_weight) ----------------
__global__ __launch_bounds__(320) void k_init(const int* __restrict__ xt,
                                              const float* __restrict__ xf,
                                              const float* __restrict__ xemb,
                                              const float* __restrict__ xw,
                                              __hip_bfloat16* __restrict__ h) {
    int n = blockIdx.x;
    int j = threadIdx.x;
    __shared__ float fs[16];
    if (j < 16) fs[j] = xf[n * 16 + j];
    __syncthreads();
    float v = 0.f;
    if (j < 300) {
        v = xemb[xt[n] * 300 + j];
        #pragma unroll
        for (int k = 0; k < 16; ++k) v += fs[k] * xw[k * 300 + j];
    }
    h[(long)n * LDK + j] = __float2bfloat16(v);
}

// ---------------- CSR build ----------------
__global__ void k_count(const int* __restrict__ ei, int* __restrict__ cnt) {
    int e = blockIdx.x * blockDim.x + threadIdx.x;
    if (e >= NTOT) return;
    int c = (e < NEDGES) ? ei[NEDGES + e] : (e - NEDGES);
    atomicAdd(&cnt[c], 1);
}

__global__ __launch_bounds__(1024) void k_scan(const int* __restrict__ cnt, int* __restrict__ off) {
    __shared__ int buf[1024];
    __shared__ int carry;
    int tid = threadIdx.x;
    if (tid == 0) carry = 0;
    __syncthreads();
    for (int base = 0; base < NNODES; base += 1024) {
        int v = (base + tid < NNODES) ? cnt[base + tid] : 0;
        buf[tid] = v;
        __syncthreads();
        for (int s = 1; s < 1024; s <<= 1) {
            int t = (tid >= s) ? buf[tid - s] : 0;
            __syncthreads();
            buf[tid] += t;
            __syncthreads();
        }
        if (base + tid < NNODES) off[base + tid] = carry + buf[tid] - v;
        __syncthreads();
        if (tid == 0) carry += buf[1023];
        __syncthreads();
    }
    if (tid == 0) off[NNODES] = carry;
}

__global__ void k_fill(const int* __restrict__ ei, const float* __restrict__ ea,
                       const int* __restrict__ off, int* __restrict__ cur,
                       EdgeRec* __restrict__ pack) {
    int e = blockIdx.x * blockDim.x + threadIdx.x;
    if (e >= NTOT) return;
    int r, c; float c0, c1;
    if (e < NEDGES) { r = ei[e]; c = ei[NEDGES + e]; c0 = ea[2 * e]; c1 = ea[2 * e + 1]; }
    else            { r = c = e - NEDGES; c0 = 0.f; c1 = 4.f; }
    int p = atomicAdd(&cur[c], 1);
    EdgeRec rec; rec.r = r; rec.c0 = c0; rec.c1 = c1;
    pack[off[c] + p] = rec;
}

// ---------------- per-layer precompute (fp32 weights): u0, u1, bias, BN scale/shift ----------------
__global__ __launch_bounds__(320) void k_prep(const float* __restrict__ W, const float* __restrict__ ew,
                                              const float* __restrict__ mb, const float* __restrict__ g,
                                              const float* __restrict__ bb, const float* __restrict__ rm,
                                              const float* __restrict__ rv, float* __restrict__ prm) {
    int j = threadIdx.x;
    if (j >= 300) return;
    float a0 = 0.f, a1 = 0.f;
    for (int k = 0; k < 300; ++k) {
        float w = W[j * 300 + k];
        a0 += w * ew[k];
        a1 += w * ew[300 + k];
    }
    prm[j] = a0;
    prm[304 + j] = a1;
    prm[608 + j] = mb[j];
    float sc = g[j] * rsqrtf(rv[j] + 1e-5f);
    prm[912 + j] = sc;
    prm[1216 + j] = bb[j] - rm[j] * sc;
}

// ---------------- MFMA GEMM: C[M,320] = A[M,320] @ B[320,320]^T, bf16 in / fp32 out ----------------
// Block 128x64, 4 waves, wave = 32x64 (2 M-tiles x 4 N-tiles of 16x16x32 MFMA)
__global__ __launch_bounds__(256) void k_gemm(const __hip_bfloat16* __restrict__ A,
                                              const __hip_bfloat16* __restrict__ B,
                                              float* __restrict__ C) {
    __shared__ __hip_bfloat16 As[128 * 32];
    __shared__ __hip_bfloat16 Bs[64 * 32];
    int tid = threadIdx.x;
    int lane = tid & 63, w = tid >> 6;
    int row0 = blockIdx.x * 128, col0 = blockIdx.y * 64;

    floatx4 acc[2][4];
    #pragma unroll
    for (int i = 0; i < 2; ++i)
        #pragma unroll
        for (int j = 0; j < 4; ++j) acc[i][j] = (floatx4){0.f, 0.f, 0.f, 0.f};

    // staging addresses: each wave stages its own 32 A rows + 16 B rows
    const __hip_bfloat16* ga0 = A + (size_t)(row0 + w * 32 + (lane >> 2)) * LDK + (lane & 3) * 8;
    const __hip_bfloat16* ga1 = ga0 + (size_t)16 * LDK;
    const __hip_bfloat16* gb  = B + (size_t)(col0 + w * 16 + (lane >> 2)) * LDK + (lane & 3) * 8;
    __hip_bfloat16* sa0 = &As[(w * 32) * 32];      // wave-uniform LDS bases
    __hip_bfloat16* sa1 = &As[(w * 32 + 16) * 32];
    __hip_bfloat16* sb  = &Bs[(w * 16) * 32];

    int m15 = lane & 15, kof = (lane >> 4) * 8;

    for (int k0 = 0; k0 < LDK; k0 += 32) {
        __syncthreads();
        gll16(ga0 + k0, sa0);
        gll16(ga1 + k0, sa1);
        gll16(gb  + k0, sb);
        __syncthreads();

        short8 a[2], b[4];
        a[0] = *(const short8*)&As[(w * 32 +      m15) * 32 + kof];
        a[1] = *(const short8*)&As[(w * 32 + 16 + m15) * 32 + kof];
        #pragma unroll
        for (int nt = 0; nt < 4; ++nt)
            b[nt] = *(const short8*)&Bs[(nt * 16 + m15) * 32 + kof];

        #pragma unroll
        for (int mt = 0; mt < 2; ++mt)
            #pragma unroll
            for (int nt = 0; nt < 4; ++nt)
                acc[mt][nt] = __builtin_amdgcn_mfma_f32_16x16x32_bf16(a[mt], b[nt], acc[mt][nt], 0, 0, 0);
    }

    // C/D layout: row = (lane>>4)*4 + i, col = lane&15
    int rbase = row0 + w * 32 + (lane >> 4) * 4;
    #pragma unroll
    for (int mt = 0; mt < 2; ++mt)
        #pragma unroll
        for (int i = 0; i < 4; ++i) {
            long gr = rbase + mt * 16 + i;
            #pragma unroll
            for (int nt = 0; nt < 4; ++nt)
                C[gr * LDK + col0 + nt * 16 + m15] = acc[mt][nt][i];
        }
}

// ---------------- aggregate: h[n] = bf16(BN( sum relu(mh[row]+c0*u0+c1*u1+b) )), wave per node ----------------
__global__ __launch_bounds__(256) void k_aggr(const float* __restrict__ mh, const EdgeRec* __restrict__ pack,
                                              const int* __restrict__ off, const float* __restrict__ prm,
                                              __hip_bfloat16* __restrict__ h, int do_relu) {
    int wave = threadIdx.x >> 6;
    int lane = threadIdx.x & 63;
    int n = blockIdx.x * 4 + wave;
    if (n >= NNODES) return;
    float u0v[5], u1v[5], bv[5], scv[5], shv[5], acc[5];
    #pragma unroll
    for (int i = 0; i < 5; ++i) {
        int j = lane + i * 64;
        bool ok = j < 300;
        u0v[i] = ok ? prm[j]        : 0.f;
        u1v[i] = ok ? prm[304 + j]  : 0.f;
        bv[i]  = ok ? prm[608 + j]  : 0.f;
        scv[i] = ok ? prm[912 + j]  : 0.f;
        shv[i] = ok ? prm[1216 + j] : 0.f;
        acc[i] = 0.f;
    }
    int p0 = off[n], p1 = off[n + 1];
    for (int p = p0; p < p1; ++p) {
        EdgeRec rec = pack[p];
        const float* base = mh + (long)rec.r * LDK;
        #pragma unroll
        for (int i = 0; i < 5; ++i) {
            int j = lane + i * 64;
            float v = (j < 300) ? base[j] : 0.f;
            v += rec.c0 * u0v[i] + rec.c1 * u1v[i] + bv[i];
            acc[i] += fmaxf(v, 0.f);
        }
    }
    #pragma unroll
    for (int i = 0; i < 5; ++i) {
        int j = lane + i * 64;
        float v = acc[i] * scv[i] + shv[i];
        if (do_relu) v = fmaxf(v, 0.f);
        h[(long)n * LDK + j] = __float2bfloat16((j < 300) ? v : 0.f);
    }
}

// ---------------- metal branch: mf, Q, qk = Q@wk, metal2 ----------------
__global__ __launch_bounds__(320) void k_metal(const int* __restrict__ mt, const float* __restrict__ mfeat,
                                               const float* __restrict__ me1w, const float* __restrict__ me1b,
                                               const float* __restrict__ me2,
                                               const float* __restrict__ wq, const float* __restrict__ wk,
                                               const float* __restrict__ mlw, const float* __restrict__ mlb,
                                               float* __restrict__ metal2, float* __restrict__ qk) {
    int b = blockIdx.x;
    int tid = threadIdx.x;
    __shared__ float fs[17];
    __shared__ float mf_s[300];
    __shared__ float q_s[256];
    if (tid < 17) fs[tid] = mfeat[b * 17 + tid];
    __syncthreads();
    if (tid < 300) {
        float v = me1b[tid] + me2[mt[b] * 300 + tid];
        #pragma unroll
        for (int k = 0; k < 17; ++k) v += fs[k] * me1w[tid * 17 + k];
        mf_s[tid] = v;
    }
    __syncthreads();
    if (tid < 256) {
        float q = 0.f, m2 = 0.f;
        for (int k = 0; k < 300; ++k) {
            float m = mf_s[k];
            q  += m * wq[tid * 300 + k];
            m2 += m * mlw[tid * 300 + k];
        }
        q_s[tid] = q;
        metal2[b * 256 + tid] = fmaxf(m2 + mlb[tid], 0.f);
    }
    __syncthreads();
    if (tid < 300) {
        float a = 0.f;
        for (int j = 0; j < 256; ++j) a += q_s[j] * wk[j * 300 + tid];
        qk[b * 300 + tid] = a;
    }
}

// ---------------- attention pool: scores -> softmax -> weighted pool + mean pool ----------------
__global__ __launch_bounds__(320) void k_pool(const __hip_bfloat16* __restrict__ h, const float* __restrict__ qk,
                                              float* __restrict__ wpool, float* __restrict__ mean) {
    int b = blockIdx.x;
    int tid = threadIdx.x;
    int wave = tid >> 6, lane = tid & 63;
    __shared__ float qk_s[300];
    __shared__ float sc[50];
    if (tid < 300) qk_s[tid] = qk[b * 300 + tid];
    __syncthreads();
    for (int k = wave; k < 50; k += 5) {
        const __hip_bfloat16* hp = h + (long)(b * 50 + k) * LDK;
        float partial = 0.f;
        #pragma unroll
        for (int i = 0; i < 5; ++i) {
            int j = lane + i * 64;
            if (j < 300) partial += __bfloat162float(hp[j]) * qk_s[j];
        }
        #pragma unroll
        for (int s = 32; s > 0; s >>= 1) partial += __shfl_xor(partial, s, 64);
        if (lane == 0) sc[k] = partial * (1.f / 16.f);
    }
    __syncthreads();
    if (tid == 0) {
        float mx = sc[0];
        for (int k = 1; k < 50; ++k) mx = fmaxf(mx, sc[k]);
        float s = 0.f;
        for (int k = 0; k < 50; ++k) { float e = __expf(sc[k] - mx); sc[k] = e; s += e; }
        float inv = 1.f / s;
        for (int k = 0; k < 50; ++k) sc[k] *= inv;
    }
    __syncthreads();
    if (tid < 300) {
        float aw = 0.f, am = 0.f;
        for (int k = 0; k < 50; ++k) {
            float v = __bfloat162float(h[(long)(b * 50 + k) * LDK + tid]);
            aw += sc[k] * v;
            am += v;
        }
        wpool[b * 300 + tid] = aw;
        mean[b * 300 + tid]  = am * (1.f / 50.f);
    }
}

// ---------------- head ----------------
__global__ __launch_bounds__(512) void k_head(const float* __restrict__ wpool, const float* __restrict__ mean,
                                              const float* __restrict__ metal2,
                                              const float* __restrict__ wv, const float* __restrict__ lgw,
                                              const float* __restrict__ lgb,
                                              const float* __restrict__ ph1w, const float* __restrict__ ph1b,
                                              const float* __restrict__ ph2w, const float* __restrict__ ph2b,
                                              float* __restrict__ out) {
    int b = blockIdx.x;
    int tid = threadIdx.x;
    __shared__ float wp_s[300], mn_s[300], f_s[256], red[512];
    if (tid < 300) { wp_s[tid] = wpool[b * 300 + tid]; mn_s[tid] = mean[b * 300 + tid]; }
    __syncthreads();
    if (tid < 256) {
        float att = 0.f, lg = 0.f;
        for (int k = 0; k < 300; ++k) {
            att += wp_s[k] * wv[tid * 300 + k];
            lg  += mn_s[k] * lgw[tid * 300 + k];
        }
        lg = fmaxf(lg + lgb[tid], 0.f);
        f_s[tid] = fmaxf(att, 0.f) + metal2[b * 256 + tid] + lg;
    }
    __syncthreads();
    float a = ph1b[tid];
    for (int k = 0; k < 256; ++k) a += f_s[k] * ph1w[tid * 256 + k];
    float sp = fmaxf(a, 0.f) + log1pf(__expf(-fabsf(a)));   // stable softplus
    red[tid] = sp * ph2w[tid];
    __syncthreads();
    for (int s = 256; s > 0; s >>= 1) {
        if (tid < s) red[tid] += red[tid + s];
        __syncthreads();
    }
    if (tid == 0) out[b] = red[0] + ph2b[0];
}

extern "C" void kernel_launch(void* const* d_in, const int* in_sizes, int n_in,
                              void* d_out, int out_size, void* d_ws, size_t ws_size,
                              hipStream_t stream) {
    const int*   x_type   = (const int*)d_in[0];
    const float* x_feat   = (const float*)d_in[1];
    const int*   eindex   = (const int*)d_in[2];
    const float* eattr    = (const float*)d_in[3];
    const int*   mtype    = (const int*)d_in[4];
    const float* mfeat    = (const float*)d_in[5];
    const float* x_emb    = (const float*)d_in[6];
    const float* x_weight = (const float*)d_in[7];
    const float* ew1      = (const float*)d_in[8];
    const float* mlp_w    = (const float*)d_in[9];
    const float* mlp_b    = (const float*)d_in[10];
    const float* bn_g     = (const float*)d_in[11];
    const float* bn_b     = (const float*)d_in[12];
    const float* bn_rm    = (const float*)d_in[13];
    const float* bn_rv    = (const float*)d_in[14];
    const float* me1_w    = (const float*)d_in[15];
    const float* me1_b    = (const float*)d_in[16];
    const float* me2      = (const float*)d_in[17];
    const float* wq       = (const float*)d_in[18];
    const float* wk       = (const float*)d_in[19];
    const float* wv       = (const float*)d_in[20];
    const float* ml_w     = (const float*)d_in[21];
    const float* ml_b     = (const float*)d_in[22];
    const float* lg_w     = (const float*)d_in[23];
    const float* lg_b     = (const float*)d_in[24];
    const float* ph1_w    = (const float*)d_in[25];
    const float* ph1_b    = (const float*)d_in[26];
    const float* ph2_w    = (const float*)d_in[27];
    const float* ph2_b    = (const float*)d_in[28];

    char* ws = (char*)d_ws;
    size_t o = 0;
    auto alloc = [&](size_t bytes) -> void* {
        void* p = ws + o;
        o += (bytes + 255) & ~(size_t)255;
        return p;
    };
    __hip_bfloat16* h    = (__hip_bfloat16*)alloc((size_t)MPAD * LDK * 2);
    float*          mh   = (float*)alloc((size_t)MPAD * LDK * 4);
    __hip_bfloat16* wb   = (__hip_bfloat16*)alloc((size_t)5 * 320 * 320 * 2);
    int*     cnt    = (int*)alloc((size_t)NNODES * 4);
    int*     offs   = (int*)alloc((size_t)(NNODES + 1) * 4);
    int*     cur    = (int*)alloc((size_t)NNODES * 4);
    EdgeRec* pack   = (EdgeRec*)alloc((size_t)NTOT * sizeof(EdgeRec));
    float*   prm    = (float*)alloc(1520 * 4);
    float*   metal2 = (float*)alloc((size_t)1000 * 256 * 4);
    float*   qk     = (float*)alloc((size_t)1000 * 300 * 4);
    float*   wpool  = (float*)alloc((size_t)1000 * 300 * 4);
    float*   meanp  = (float*)alloc((size_t)1000 * 300 * 4);
    (void)ws_size; (void)in_sizes; (void)n_in; (void)out_size;

    hipMemsetAsync(cnt, 0, (size_t)NNODES * 4, stream);
    hipMemsetAsync(cur, 0, (size_t)NNODES * 4, stream);

    k_cvt<<<(5 * 320 * 320 + 255) / 256, 256, 0, stream>>>(mlp_w, wb);
    k_init<<<NNODES, 320, 0, stream>>>(x_type, x_feat, x_emb, x_weight, h);
    k_count<<<(NTOT + 255) / 256, 256, 0, stream>>>(eindex, cnt);
    k_scan<<<1, 1024, 0, stream>>>(cnt, offs);
    k_fill<<<(NTOT + 255) / 256, 256, 0, stream>>>(eindex, eattr, offs, cur, pack);

    for (int l = 0; l < NLAYERS; ++l) {
        k_prep<<<1, 320, 0, stream>>>(mlp_w + (size_t)l * 90000, ew1 + l * 600, mlp_b + l * 300,
                                      bn_g + l * 300, bn_b + l * 300, bn_rm + l * 300,
                                      bn_rv + l * 300, prm);
        dim3 g(MPAD / 128, 5);
        k_gemm<<<g, 256, 0, stream>>>(h, wb + (size_t)l * 102400, mh);
        k_aggr<<<(NNODES + 3) / 4, 256, 0, stream>>>(mh, pack, offs, prm, h, (l < NLAYERS - 1) ? 1 : 0);
    }

    k_metal<<<1000, 320, 0, stream>>>(mtype, mfeat, me1_w, me1_b, me2, wq, wk, ml_w, ml_b, metal2, qk);
    k_pool<<<1000, 320, 0, stream>>>(h, qk, wpool, meanp);
    k_head<<<1000, 512, 0, stream>>>(wpool, meanp, metal2, wv, lg_w, lg_b,
                                     ph1_w, ph1_b, ph2_w, ph2_b, (float*)d_out);
}

// Round 3
// 933.834 us; speedup vs baseline: 1.7864x; 1.1176x over previous
//
#include <hip/hip_runtime.h>
#include <hip/hip_bf16.h>
#include <math.h>

#define NNODES  50000
#define NEDGES  200000
#define NTOT    250000      // E + N self loops
#define EMB     300
#define LDK     320         // padded K stride (bf16 h, bf16 weights, fp32 mh)
#define MPAD    50048       // 391 * 128 (GEMM M padding)
#define NLAYERS 5

struct EdgeRec { int r; float c0, c1; };

typedef __attribute__((ext_vector_type(8))) short short8;
typedef __attribute__((ext_vector_type(4))) float floatx4;

__device__ inline void gll16(const void* g, void* s) {
    __builtin_amdgcn_global_load_lds((const __attribute__((address_space(1))) unsigned*)g,
                                     (__attribute__((address_space(3))) unsigned*)s, 16, 0, 0);
}

// ---------------- generic transpose: dst[c*R+r] = src[r*C+c] ----------------
__global__ void k_tr(const float* __restrict__ src, float* __restrict__ dst, int R, int C) {
    int idx = blockIdx.x * 256 + threadIdx.x;
    if (idx >= R * C) return;
    int r = idx / C, c = idx % C;
    dst[c * R + r] = src[idx];
}

// ---------------- weight convert: wb[l][320][320] = bf16(mlp_w[l][300][300]) zero-padded ----------------
__global__ void k_cvt(const float* __restrict__ w, __hip_bfloat16* __restrict__ wb) {
    int idx = blockIdx.x * 256 + threadIdx.x;
    if (idx >= 5 * 320 * 320) return;
    int l = idx / 102400, r = idx % 102400, n = r / 320, k = r % 320;
    float v = (n < 300 && k < 300) ? w[l * 90000 + n * 300 + k] : 0.f;
    wb[idx] = __float2bfloat16(v);
}

// ---------------- node init: h = bf16(x_emb[x_type] + x_feat @ x_weight) ----------------
__global__ __launch_bounds__(320) void k_init(const int* __restrict__ xt,
                                              const float* __restrict__ xf,
                                              const float* __restrict__ xemb,
                                              const float* __restrict__ xw,
                                              __hip_bfloat16* __restrict__ h) {
    int n = blockIdx.x;
    int j = threadIdx.x;
    __shared__ float fs[16];
    if (j < 16) fs[j] = xf[n * 16 + j];
    __syncthreads();
    float v = 0.f;
    if (j < 300) {
        v = xemb[xt[n] * 300 + j];
        #pragma unroll
        for (int k = 0; k < 16; ++k) v += fs[k] * xw[k * 300 + j];
    }
    h[(long)n * LDK + j] = __float2bfloat16(v);
}

// ---------------- CSR build ----------------
__global__ void k_count(const int* __restrict__ ei, int* __restrict__ cnt) {
    int e = blockIdx.x * blockDim.x + threadIdx.x;
    if (e >= NTOT) return;
    int c = (e < NEDGES) ? ei[NEDGES + e] : (e - NEDGES);
    atomicAdd(&cnt[c], 1);
}

__global__ __launch_bounds__(1024) void k_scan(const int* __restrict__ cnt, int* __restrict__ off) {
    __shared__ int buf[1024];
    __shared__ int carry;
    int tid = threadIdx.x;
    if (tid == 0) carry = 0;
    __syncthreads();
    for (int base = 0; base < NNODES; base += 1024) {
        int v = (base + tid < NNODES) ? cnt[base + tid] : 0;
        buf[tid] = v;
        __syncthreads();
        for (int s = 1; s < 1024; s <<= 1) {
            int t = (tid >= s) ? buf[tid - s] : 0;
            __syncthreads();
            buf[tid] += t;
            __syncthreads();
        }
        if (base + tid < NNODES) off[base + tid] = carry + buf[tid] - v;
        __syncthreads();
        if (tid == 0) carry += buf[1023];
        __syncthreads();
    }
    if (tid == 0) off[NNODES] = carry;
}

__global__ void k_fill(const int* __restrict__ ei, const float* __restrict__ ea,
                       const int* __restrict__ off, int* __restrict__ cur,
                       EdgeRec* __restrict__ pack) {
    int e = blockIdx.x * blockDim.x + threadIdx.x;
    if (e >= NTOT) return;
    int r, c; float c0, c1;
    if (e < NEDGES) { r = ei[e]; c = ei[NEDGES + e]; c0 = ea[2 * e]; c1 = ea[2 * e + 1]; }
    else            { r = c = e - NEDGES; c0 = 0.f; c1 = 4.f; }
    int p = atomicAdd(&cur[c], 1);
    EdgeRec rec; rec.r = r; rec.c0 = c0; rec.c1 = c1;
    pack[off[c] + p] = rec;
}

// ---------------- per-layer precompute (fp32 weights): u0, u1, bias, BN scale/shift ----------------
__global__ __launch_bounds__(320) void k_prep(const float* __restrict__ W, const float* __restrict__ ew,
                                              const float* __restrict__ mb, const float* __restrict__ g,
                                              const float* __restrict__ bb, const float* __restrict__ rm,
                                              const float* __restrict__ rv, float* __restrict__ prm) {
    int j = threadIdx.x;
    if (j >= 300) return;
    float a0 = 0.f, a1 = 0.f;
    for (int k = 0; k < 300; ++k) {
        float w = W[j * 300 + k];
        a0 += w * ew[k];
        a1 += w * ew[300 + k];
    }
    prm[j] = a0;
    prm[304 + j] = a1;
    prm[608 + j] = mb[j];
    float sc = g[j] * rsqrtf(rv[j] + 1e-5f);
    prm[912 + j] = sc;
    prm[1216 + j] = bb[j] - rm[j] * sc;
}

// ---------------- MFMA GEMM: C[M,320] = A[M,320] @ B[320,320]^T, bf16 in / fp32 out ----------------
__global__ __launch_bounds__(256) void k_gemm(const __hip_bfloat16* __restrict__ A,
                                              const __hip_bfloat16* __restrict__ B,
                                              float* __restrict__ C) {
    __shared__ __hip_bfloat16 As[128 * 32];
    __shared__ __hip_bfloat16 Bs[64 * 32];
    int tid = threadIdx.x;
    int lane = tid & 63, w = tid >> 6;
    int row0 = blockIdx.x * 128, col0 = blockIdx.y * 64;

    floatx4 acc[2][4];
    #pragma unroll
    for (int i = 0; i < 2; ++i)
        #pragma unroll
        for (int j = 0; j < 4; ++j) acc[i][j] = (floatx4){0.f, 0.f, 0.f, 0.f};

    const __hip_bfloat16* ga0 = A + (size_t)(row0 + w * 32 + (lane >> 2)) * LDK + (lane & 3) * 8;
    const __hip_bfloat16* ga1 = ga0 + (size_t)16 * LDK;
    const __hip_bfloat16* gb  = B + (size_t)(col0 + w * 16 + (lane >> 2)) * LDK + (lane & 3) * 8;
    __hip_bfloat16* sa0 = &As[(w * 32) * 32];
    __hip_bfloat16* sa1 = &As[(w * 32 + 16) * 32];
    __hip_bfloat16* sb  = &Bs[(w * 16) * 32];

    int m15 = lane & 15, kof = (lane >> 4) * 8;

    for (int k0 = 0; k0 < LDK; k0 += 32) {
        __syncthreads();
        gll16(ga0 + k0, sa0);
        gll16(ga1 + k0, sa1);
        gll16(gb  + k0, sb);
        __syncthreads();

        short8 a[2], b[4];
        a[0] = *(const short8*)&As[(w * 32 +      m15) * 32 + kof];
        a[1] = *(const short8*)&As[(w * 32 + 16 + m15) * 32 + kof];
        #pragma unroll
        for (int nt = 0; nt < 4; ++nt)
            b[nt] = *(const short8*)&Bs[(nt * 16 + m15) * 32 + kof];

        #pragma unroll
        for (int mt = 0; mt < 2; ++mt)
            #pragma unroll
            for (int nt = 0; nt < 4; ++nt)
                acc[mt][nt] = __builtin_amdgcn_mfma_f32_16x16x32_bf16(a[mt], b[nt], acc[mt][nt], 0, 0, 0);
    }

    int rbase = row0 + w * 32 + (lane >> 4) * 4;
    #pragma unroll
    for (int mt = 0; mt < 2; ++mt)
        #pragma unroll
        for (int i = 0; i < 4; ++i) {
            long gr = rbase + mt * 16 + i;
            #pragma unroll
            for (int nt = 0; nt < 4; ++nt)
                C[gr * LDK + col0 + nt * 16 + m15] = acc[mt][nt][i];
        }
}

// ---------------- aggregate ----------------
__global__ __launch_bounds__(256) void k_aggr(const float* __restrict__ mh, const EdgeRec* __restrict__ pack,
                                              const int* __restrict__ off, const float* __restrict__ prm,
                                              __hip_bfloat16* __restrict__ h, int do_relu) {
    int wave = threadIdx.x >> 6;
    int lane = threadIdx.x & 63;
    int n = blockIdx.x * 4 + wave;
    if (n >= NNODES) return;
    float u0v[5], u1v[5], bv[5], scv[5], shv[5], acc[5];
    #pragma unroll
    for (int i = 0; i < 5; ++i) {
        int j = lane + i * 64;
        bool ok = j < 300;
        u0v[i] = ok ? prm[j]        : 0.f;
        u1v[i] = ok ? prm[304 + j]  : 0.f;
        bv[i]  = ok ? prm[608 + j]  : 0.f;
        scv[i] = ok ? prm[912 + j]  : 0.f;
        shv[i] = ok ? prm[1216 + j] : 0.f;
        acc[i] = 0.f;
    }
    int p0 = off[n], p1 = off[n + 1];
    for (int p = p0; p < p1; ++p) {
        EdgeRec rec = pack[p];
        const float* base = mh + (long)rec.r * LDK;
        #pragma unroll
        for (int i = 0; i < 5; ++i) {
            int j = lane + i * 64;
            float v = (j < 300) ? base[j] : 0.f;
            v += rec.c0 * u0v[i] + rec.c1 * u1v[i] + bv[i];
            acc[i] += fmaxf(v, 0.f);
        }
    }
    #pragma unroll
    for (int i = 0; i < 5; ++i) {
        int j = lane + i * 64;
        float v = acc[i] * scv[i] + shv[i];
        if (do_relu) v = fmaxf(v, 0.f);
        h[(long)n * LDK + j] = __float2bfloat16((j < 300) ? v : 0.f);
    }
}

// ---------------- metal branch (coalesced via transposed weights) ----------------
__global__ __launch_bounds__(320) void k_metal(const int* __restrict__ mt, const float* __restrict__ mfeat,
                                               const float* __restrict__ me1wT, const float* __restrict__ me1b,
                                               const float* __restrict__ me2,
                                               const float* __restrict__ wqT, const float* __restrict__ wk,
                                               const float* __restrict__ mlwT, const float* __restrict__ mlb,
                                               float* __restrict__ metal2, float* __restrict__ qk) {
    int b = blockIdx.x;
    int tid = threadIdx.x;
    __shared__ float fs[17];
    __shared__ float mf_s[300];
    __shared__ float q_s[256];
    if (tid < 17) fs[tid] = mfeat[b * 17 + tid];
    __syncthreads();
    if (tid < 300) {
        float v = me1b[tid] + me2[mt[b] * 300 + tid];
        #pragma unroll
        for (int k = 0; k < 17; ++k) v += fs[k] * me1wT[k * 300 + tid];
        mf_s[tid] = v;
    }
    __syncthreads();
    if (tid < 256) {
        float q = 0.f, m2 = 0.f;
        #pragma unroll 4
        for (int k = 0; k < 300; ++k) {
            float m = mf_s[k];
            q  += m * wqT[k * 256 + tid];
            m2 += m * mlwT[k * 256 + tid];
        }
        q_s[tid] = q;
        metal2[b * 256 + tid] = fmaxf(m2 + mlb[tid], 0.f);
    }
    __syncthreads();
    if (tid < 300) {
        float a = 0.f;
        #pragma unroll 4
        for (int j = 0; j < 256; ++j) a += q_s[j] * wk[j * 300 + tid];
        qk[b * 300 + tid] = a;
    }
}

// ---------------- attention pool ----------------
__global__ __launch_bounds__(320) void k_pool(const __hip_bfloat16* __restrict__ h, const float* __restrict__ qk,
                                              float* __restrict__ wpool, float* __restrict__ mean) {
    int b = blockIdx.x;
    int tid = threadIdx.x;
    int wave = tid >> 6, lane = tid & 63;
    __shared__ float qk_s[300];
    __shared__ float sc[50];
    if (tid < 300) qk_s[tid] = qk[b * 300 + tid];
    __syncthreads();
    for (int k = wave; k < 50; k += 5) {
        const __hip_bfloat16* hp = h + (long)(b * 50 + k) * LDK;
        float partial = 0.f;
        #pragma unroll
        for (int i = 0; i < 5; ++i) {
            int j = lane + i * 64;
            if (j < 300) partial += __bfloat162float(hp[j]) * qk_s[j];
        }
        #pragma unroll
        for (int s = 32; s > 0; s >>= 1) partial += __shfl_xor(partial, s, 64);
        if (lane == 0) sc[k] = partial * (1.f / 16.f);
    }
    __syncthreads();
    if (tid == 0) {
        float mx = sc[0];
        for (int k = 1; k < 50; ++k) mx = fmaxf(mx, sc[k]);
        float s = 0.f;
        for (int k = 0; k < 50; ++k) { float e = __expf(sc[k] - mx); sc[k] = e; s += e; }
        float inv = 1.f / s;
        for (int k = 0; k < 50; ++k) sc[k] *= inv;
    }
    __syncthreads();
    if (tid < 300) {
        float aw = 0.f, am = 0.f;
        for (int k = 0; k < 50; ++k) {
            float v = __bfloat162float(h[(long)(b * 50 + k) * LDK + tid]);
            aw += sc[k] * v;
            am += v;
        }
        wpool[b * 300 + tid] = aw;
        mean[b * 300 + tid]  = am * (1.f / 50.f);
    }
}

// ---------------- head (coalesced via transposed weights) ----------------
__global__ __launch_bounds__(512) void k_head(const float* __restrict__ wpool, const float* __restrict__ mean,
                                              const float* __restrict__ metal2,
                                              const float* __restrict__ wvT, const float* __restrict__ lgwT,
                                              const float* __restrict__ lgb,
                                              const float* __restrict__ ph1wT, const float* __restrict__ ph1b,
                                              const float* __restrict__ ph2w, const float* __restrict__ ph2b,
                                              float* __restrict__ out) {
    int b = blockIdx.x;
    int tid = threadIdx.x;
    __shared__ float wp_s[300], mn_s[300], f_s[256], red[512];
    if (tid < 300) { wp_s[tid] = wpool[b * 300 + tid]; mn_s[tid] = mean[b * 300 + tid]; }
    __syncthreads();
    if (tid < 256) {
        float att = 0.f, lg = 0.f;
        #pragma unroll 4
        for (int k = 0; k < 300; ++k) {
            att += wp_s[k] * wvT[k * 256 + tid];
            lg  += mn_s[k] * lgwT[k * 256 + tid];
        }
        lg = fmaxf(lg + lgb[tid], 0.f);
        f_s[tid] = fmaxf(att, 0.f) + metal2[b * 256 + tid] + lg;
    }
    __syncthreads();
    float a = ph1b[tid];
    #pragma unroll 8
    for (int k = 0; k < 256; ++k) a += f_s[k] * ph1wT[k * 512 + tid];
    float sp = fmaxf(a, 0.f) + log1pf(__expf(-fabsf(a)));   // stable softplus
    red[tid] = sp * ph2w[tid];
    __syncthreads();
    for (int s = 256; s > 0; s >>= 1) {
        if (tid < s) red[tid] += red[tid + s];
        __syncthreads();
    }
    if (tid == 0) out[b] = red[0] + ph2b[0];
}

extern "C" void kernel_launch(void* const* d_in, const int* in_sizes, int n_in,
                              void* d_out, int out_size, void* d_ws, size_t ws_size,
                              hipStream_t stream) {
    const int*   x_type   = (const int*)d_in[0];
    const float* x_feat   = (const float*)d_in[1];
    const int*   eindex   = (const int*)d_in[2];
    const float* eattr    = (const float*)d_in[3];
    const int*   mtype    = (const int*)d_in[4];
    const float* mfeat    = (const float*)d_in[5];
    const float* x_emb    = (const float*)d_in[6];
    const float* x_weight = (const float*)d_in[7];
    const float* ew1      = (const float*)d_in[8];
    const float* mlp_w    = (const float*)d_in[9];
    const float* mlp_b    = (const float*)d_in[10];
    const float* bn_g     = (const float*)d_in[11];
    const float* bn_b     = (const float*)d_in[12];
    const float* bn_rm    = (const float*)d_in[13];
    const float* bn_rv    = (const float*)d_in[14];
    const float* me1_w    = (const float*)d_in[15];
    const float* me1_b    = (const float*)d_in[16];
    const float* me2      = (const float*)d_in[17];
    const float* wq       = (const float*)d_in[18];
    const float* wk       = (const float*)d_in[19];
    const float* wv       = (const float*)d_in[20];
    const float* ml_w     = (const float*)d_in[21];
    const float* ml_b     = (const float*)d_in[22];
    const float* lg_w     = (const float*)d_in[23];
    const float* lg_b     = (const float*)d_in[24];
    const float* ph1_w    = (const float*)d_in[25];
    const float* ph1_b    = (const float*)d_in[26];
    const float* ph2_w    = (const float*)d_in[27];
    const float* ph2_b    = (const float*)d_in[28];

    char* ws = (char*)d_ws;
    size_t o = 0;
    auto alloc = [&](size_t bytes) -> void* {
        void* p = ws + o;
        o += (bytes + 255) & ~(size_t)255;
        return p;
    };
    __hip_bfloat16* h    = (__hip_bfloat16*)alloc((size_t)MPAD * LDK * 2);
    float*          mh   = (float*)alloc((size_t)MPAD * LDK * 4);
    __hip_bfloat16* wb   = (__hip_bfloat16*)alloc((size_t)5 * 320 * 320 * 2);
    int*     cnt    = (int*)alloc((size_t)NNODES * 4);
    int*     offs   = (int*)alloc((size_t)(NNODES + 1) * 4);
    int*     cur    = (int*)alloc((size_t)NNODES * 4);
    EdgeRec* pack   = (EdgeRec*)alloc((size_t)NTOT * sizeof(EdgeRec));
    float*   prm    = (float*)alloc(1520 * 4);
    float*   metal2 = (float*)alloc((size_t)1000 * 256 * 4);
    float*   qk     = (float*)alloc((size_t)1000 * 300 * 4);
    float*   wpool  = (float*)alloc((size_t)1000 * 300 * 4);
    float*   meanp  = (float*)alloc((size_t)1000 * 300 * 4);
    float*   wqT    = (float*)alloc((size_t)300 * 256 * 4);
    float*   mlwT   = (float*)alloc((size_t)300 * 256 * 4);
    float*   wvT    = (float*)alloc((size_t)300 * 256 * 4);
    float*   lgwT   = (float*)alloc((size_t)300 * 256 * 4);
    float*   ph1wT  = (float*)alloc((size_t)256 * 512 * 4);
    float*   me1wT  = (float*)alloc((size_t)17 * 300 * 4);
    (void)ws_size; (void)in_sizes; (void)n_in; (void)out_size;

    hipMemsetAsync(cnt, 0, (size_t)NNODES * 4, stream);
    hipMemsetAsync(cur, 0, (size_t)NNODES * 4, stream);

    k_cvt<<<(5 * 320 * 320 + 255) / 256, 256, 0, stream>>>(mlp_w, wb);
    k_tr<<<(256 * 300 + 255) / 256, 256, 0, stream>>>(wq, wqT, 256, 300);
    k_tr<<<(256 * 300 + 255) / 256, 256, 0, stream>>>(ml_w, mlwT, 256, 300);
    k_tr<<<(256 * 300 + 255) / 256, 256, 0, stream>>>(wv, wvT, 256, 300);
    k_tr<<<(256 * 300 + 255) / 256, 256, 0, stream>>>(lg_w, lgwT, 256, 300);
    k_tr<<<(512 * 256 + 255) / 256, 256, 0, stream>>>(ph1_w, ph1wT, 512, 256);
    k_tr<<<(300 * 17 + 255) / 256, 256, 0, stream>>>(me1_w, me1wT, 300, 17);
    k_init<<<NNODES, 320, 0, stream>>>(x_type, x_feat, x_emb, x_weight, h);
    k_count<<<(NTOT + 255) / 256, 256, 0, stream>>>(eindex, cnt);
    k_scan<<<1, 1024, 0, stream>>>(cnt, offs);
    k_fill<<<(NTOT + 255) / 256, 256, 0, stream>>>(eindex, eattr, offs, cur, pack);

    for (int l = 0; l < NLAYERS; ++l) {
        k_prep<<<1, 320, 0, stream>>>(mlp_w + (size_t)l * 90000, ew1 + l * 600, mlp_b + l * 300,
                                      bn_g + l * 300, bn_b + l * 300, bn_rm + l * 300,
                                      bn_rv + l * 300, prm);
        dim3 g(MPAD / 128, 5);
        k_gemm<<<g, 256, 0, stream>>>(h, wb + (size_t)l * 102400, mh);
        k_aggr<<<(NNODES + 3) / 4, 256, 0, stream>>>(mh, pack, offs, prm, h, (l < NLAYERS - 1) ? 1 : 0);
    }

    k_metal<<<1000, 320, 0, stream>>>(mtype, mfeat, me1wT, me1_b, me2, wqT, wk, mlwT, ml_b, metal2, qk);
    k_pool<<<1000, 320, 0, stream>>>(h, qk, wpool, meanp);
    k_head<<<1000, 512, 0, stream>>>(wpool, meanp, metal2, wvT, lgwT, lg_b,
                                     ph1wT, ph1_b, ph2_w, ph2_b, (float*)d_out);
}

// Round 4
// 852.242 us; speedup vs baseline: 1.9575x; 1.0957x over previous
//
#include <hip/hip_runtime.h>
#include <hip/hip_bf16.h>
#include <math.h>

#define NNODES  50000
#define NEDGES  200000
#define NTOT    250000      // E + N self loops
#define EMB     300
#define LDK     320         // padded K stride (bf16 h, bf16 weights, fp32 mh)
#define MPAD    50048       // 391 * 128 (GEMM M padding)
#define NLAYERS 5
#define NSCAN   49          // ceil(NNODES / 1024)

struct EdgeRec { int r; float c0, c1; };

typedef __attribute__((ext_vector_type(8))) short short8;
typedef __attribute__((ext_vector_type(4))) float floatx4;

__device__ inline void gll16(const void* g, void* s) {
    __builtin_amdgcn_global_load_lds((const __attribute__((address_space(1))) unsigned*)g,
                                     (__attribute__((address_space(3))) unsigned*)s, 16, 0, 0);
}

// ---------------- generic transpose: dst[c*R+r] = src[r*C+c] ----------------
__global__ void k_tr(const float* __restrict__ src, float* __restrict__ dst, int R, int C) {
    int idx = blockIdx.x * 256 + threadIdx.x;
    if (idx >= R * C) return;
    int r = idx / C, c = idx % C;
    dst[c * R + r] = src[idx];
}

// ---------------- weight convert: wb[l][320][320] = bf16(mlp_w[l][300][300]) zero-padded ----------------
__global__ void k_cvt(const float* __restrict__ w, __hip_bfloat16* __restrict__ wb) {
    int idx = blockIdx.x * 256 + threadIdx.x;
    if (idx >= 5 * 320 * 320) return;
    int l = idx / 102400, r = idx % 102400, n = r / 320, k = r % 320;
    float v = (n < 300 && k < 300) ? w[l * 90000 + n * 300 + k] : 0.f;
    wb[idx] = __float2bfloat16(v);
}

// ---------------- node init: h = bf16(x_emb[x_type] + x_feat @ x_weight) ----------------
__global__ __launch_bounds__(320) void k_init(const int* __restrict__ xt,
                                              const float* __restrict__ xf,
                                              const float* __restrict__ xemb,
                                              const float* __restrict__ xw,
                                              __hip_bfloat16* __restrict__ h) {
    int n = blockIdx.x;
    int j = threadIdx.x;
    __shared__ float fs[16];
    if (j < 16) fs[j] = xf[n * 16 + j];
    __syncthreads();
    float v = 0.f;
    if (j < 300) {
        v = xemb[xt[n] * 300 + j];
        #pragma unroll
        for (int k = 0; k < 16; ++k) v += fs[k] * xw[k * 300 + j];
    }
    h[(long)n * LDK + j] = __float2bfloat16(v);
}

// ---------------- CSR build ----------------
__global__ void k_count(const int* __restrict__ ei, int* __restrict__ cnt) {
    int e = blockIdx.x * blockDim.x + threadIdx.x;
    if (e >= NTOT) return;
    int c = (e < NEDGES) ? ei[NEDGES + e] : (e - NEDGES);
    atomicAdd(&cnt[c], 1);
}

// hierarchical exclusive scan: per-block scan (shfl) + block sums
__global__ __launch_bounds__(1024) void k_scan1(const int* __restrict__ cnt, int* __restrict__ off,
                                                int* __restrict__ bsum) {
    int tid = threadIdx.x;
    int gid = blockIdx.x * 1024 + tid;
    int lane = tid & 63, wv = tid >> 6;
    int v = (gid < NNODES) ? cnt[gid] : 0;
    int x = v;
    #pragma unroll
    for (int s = 1; s < 64; s <<= 1) {
        int t = __shfl_up(x, s, 64);
        if (lane >= s) x += t;
    }
    __shared__ int wsum[16];
    if (lane == 63) wsum[wv] = x;
    __syncthreads();
    if (wv == 0) {
        int w = (lane < 16) ? wsum[lane] : 0;
        #pragma unroll
        for (int s = 1; s < 16; s <<= 1) {
            int t = __shfl_up(w, s, 64);
            if (lane >= s) w += t;
        }
        if (lane < 16) wsum[lane] = w;
    }
    __syncthreads();
    int base = (wv > 0) ? wsum[wv - 1] : 0;
    int incl = x + base;
    if (gid < NNODES) off[gid] = incl - v;     // block-local exclusive
    if (tid == 1023) bsum[blockIdx.x] = incl;  // block total
}

__global__ __launch_bounds__(64) void k_scan2(int* __restrict__ bsum) {
    int lane = threadIdx.x;
    int v = (lane < NSCAN) ? bsum[lane] : 0;
    int x = v;
    #pragma unroll
    for (int s = 1; s < 64; s <<= 1) {
        int t = __shfl_up(x, s, 64);
        if (lane >= s) x += t;
    }
    if (lane < NSCAN) bsum[lane] = x - v;      // exclusive block offsets
}

__global__ __launch_bounds__(1024) void k_scan3(int* __restrict__ off, const int* __restrict__ bsum) {
    int gid = blockIdx.x * 1024 + threadIdx.x;
    if (gid < NNODES) off[gid] += bsum[blockIdx.x];
    if (gid == 0) off[NNODES] = NTOT;
}

__global__ void k_fill(const int* __restrict__ ei, const float* __restrict__ ea,
                       const int* __restrict__ off, int* __restrict__ cur,
                       EdgeRec* __restrict__ pack) {
    int e = blockIdx.x * blockDim.x + threadIdx.x;
    if (e >= NTOT) return;
    int r, c; float c0, c1;
    if (e < NEDGES) { r = ei[e]; c = ei[NEDGES + e]; c0 = ea[2 * e]; c1 = ea[2 * e + 1]; }
    else            { r = c = e - NEDGES; c0 = 0.f; c1 = 4.f; }
    int p = atomicAdd(&cur[c], 1);
    EdgeRec rec; rec.r = r; rec.c0 = c0; rec.c1 = c1;
    pack[off[c] + p] = rec;
}

// ---------------- per-layer precompute (fp32 weights): u0, u1, bias, BN scale/shift ----------------
__global__ __launch_bounds__(320) void k_prep(const float* __restrict__ W, const float* __restrict__ ew,
                                              const float* __restrict__ mb, const float* __restrict__ g,
                                              const float* __restrict__ bb, const float* __restrict__ rm,
                                              const float* __restrict__ rv, float* __restrict__ prm) {
    int j = threadIdx.x;
    if (j >= 300) return;
    float a0 = 0.f, a1 = 0.f;
    for (int k = 0; k < 300; ++k) {
        float w = W[j * 300 + k];
        a0 += w * ew[k];
        a1 += w * ew[300 + k];
    }
    prm[j] = a0;
    prm[304 + j] = a1;
    prm[608 + j] = mb[j];
    float sc = g[j] * rsqrtf(rv[j] + 1e-5f);
    prm[912 + j] = sc;
    prm[1216 + j] = bb[j] - rm[j] * sc;
}

// ---------------- MFMA GEMM: C[M,320] = A[M,320] @ B[320,320]^T, bf16 in / fp32 out ----------------
__global__ __launch_bounds__(256) void k_gemm(const __hip_bfloat16* __restrict__ A,
                                              const __hip_bfloat16* __restrict__ B,
                                              float* __restrict__ C) {
    __shared__ __hip_bfloat16 As[128 * 32];
    __shared__ __hip_bfloat16 Bs[64 * 32];
    int tid = threadIdx.x;
    int lane = tid & 63, w = tid >> 6;
    int row0 = blockIdx.x * 128, col0 = blockIdx.y * 64;

    floatx4 acc[2][4];
    #pragma unroll
    for (int i = 0; i < 2; ++i)
        #pragma unroll
        for (int j = 0; j < 4; ++j) acc[i][j] = (floatx4){0.f, 0.f, 0.f, 0.f};

    const __hip_bfloat16* ga0 = A + (size_t)(row0 + w * 32 + (lane >> 2)) * LDK + (lane & 3) * 8;
    const __hip_bfloat16* ga1 = ga0 + (size_t)16 * LDK;
    const __hip_bfloat16* gb  = B + (size_t)(col0 + w * 16 + (lane >> 2)) * LDK + (lane & 3) * 8;
    __hip_bfloat16* sa0 = &As[(w * 32) * 32];
    __hip_bfloat16* sa1 = &As[(w * 32 + 16) * 32];
    __hip_bfloat16* sb  = &Bs[(w * 16) * 32];

    int m15 = lane & 15, kof = (lane >> 4) * 8;

    for (int k0 = 0; k0 < LDK; k0 += 32) {
        __syncthreads();
        gll16(ga0 + k0, sa0);
        gll16(ga1 + k0, sa1);
        gll16(gb  + k0, sb);
        __syncthreads();

        short8 a[2], b[4];
        a[0] = *(const short8*)&As[(w * 32 +      m15) * 32 + kof];
        a[1] = *(const short8*)&As[(w * 32 + 16 + m15) * 32 + kof];
        #pragma unroll
        for (int nt = 0; nt < 4; ++nt)
            b[nt] = *(const short8*)&Bs[(nt * 16 + m15) * 32 + kof];

        #pragma unroll
        for (int mt = 0; mt < 2; ++mt)
            #pragma unroll
            for (int nt = 0; nt < 4; ++nt)
                acc[mt][nt] = __builtin_amdgcn_mfma_f32_16x16x32_bf16(a[mt], b[nt], acc[mt][nt], 0, 0, 0);
    }

    int rbase = row0 + w * 32 + (lane >> 4) * 4;
    #pragma unroll
    for (int mt = 0; mt < 2; ++mt)
        #pragma unroll
        for (int i = 0; i < 4; ++i) {
            long gr = rbase + mt * 16 + i;
            #pragma unroll
            for (int nt = 0; nt < 4; ++nt)
                C[gr * LDK + col0 + nt * 16 + m15] = acc[mt][nt][i];
        }
}

// ---------------- aggregate ----------------
__global__ __launch_bounds__(256) void k_aggr(const float* __restrict__ mh, const EdgeRec* __restrict__ pack,
                                              const int* __restrict__ off, const float* __restrict__ prm,
                                              __hip_bfloat16* __restrict__ h, int do_relu) {
    int wave = threadIdx.x >> 6;
    int lane = threadIdx.x & 63;
    int n = blockIdx.x * 4 + wave;
    if (n >= NNODES) return;
    float u0v[5], u1v[5], bv[5], scv[5], shv[5], acc[5];
    #pragma unroll
    for (int i = 0; i < 5; ++i) {
        int j = lane + i * 64;
        bool ok = j < 300;
        u0v[i] = ok ? prm[j]        : 0.f;
        u1v[i] = ok ? prm[304 + j]  : 0.f;
        bv[i]  = ok ? prm[608 + j]  : 0.f;
        scv[i] = ok ? prm[912 + j]  : 0.f;
        shv[i] = ok ? prm[1216 + j] : 0.f;
        acc[i] = 0.f;
    }
    int p0 = off[n], p1 = off[n + 1];
    for (int p = p0; p < p1; ++p) {
        EdgeRec rec = pack[p];
        const float* base = mh + (long)rec.r * LDK;
        #pragma unroll
        for (int i = 0; i < 5; ++i) {
            int j = lane + i * 64;
            float v = (j < 300) ? base[j] : 0.f;
            v += rec.c0 * u0v[i] + rec.c1 * u1v[i] + bv[i];
            acc[i] += fmaxf(v, 0.f);
        }
    }
    #pragma unroll
    for (int i = 0; i < 5; ++i) {
        int j = lane + i * 64;
        float v = acc[i] * scv[i] + shv[i];
        if (do_relu) v = fmaxf(v, 0.f);
        h[(long)n * LDK + j] = __float2bfloat16((j < 300) ? v : 0.f);
    }
}

// ---------------- metal branch (coalesced via transposed weights) ----------------
__global__ __launch_bounds__(320) void k_metal(const int* __restrict__ mt, const float* __restrict__ mfeat,
                                               const float* __restrict__ me1wT, const float* __restrict__ me1b,
                                               const float* __restrict__ me2,
                                               const float* __restrict__ wqT, const float* __restrict__ wk,
                                               const float* __restrict__ mlwT, const float* __restrict__ mlb,
                                               float* __restrict__ metal2, float* __restrict__ qk) {
    int b = blockIdx.x;
    int tid = threadIdx.x;
    __shared__ float fs[17];
    __shared__ float mf_s[300];
    __shared__ float q_s[256];
    if (tid < 17) fs[tid] = mfeat[b * 17 + tid];
    __syncthreads();
    if (tid < 300) {
        float v = me1b[tid] + me2[mt[b] * 300 + tid];
        #pragma unroll
        for (int k = 0; k < 17; ++k) v += fs[k] * me1wT[k * 300 + tid];
        mf_s[tid] = v;
    }
    __syncthreads();
    if (tid < 256) {
        float q = 0.f, m2 = 0.f;
        #pragma unroll 4
        for (int k = 0; k < 300; ++k) {
            float m = mf_s[k];
            q  += m * wqT[k * 256 + tid];
            m2 += m * mlwT[k * 256 + tid];
        }
        q_s[tid] = q;
        metal2[b * 256 + tid] = fmaxf(m2 + mlb[tid], 0.f);
    }
    __syncthreads();
    if (tid < 300) {
        float a = 0.f;
        #pragma unroll 4
        for (int j = 0; j < 256; ++j) a += q_s[j] * wk[j * 300 + tid];
        qk[b * 300 + tid] = a;
    }
}

// ---------------- attention pool ----------------
__global__ __launch_bounds__(320) void k_pool(const __hip_bfloat16* __restrict__ h, const float* __restrict__ qk,
                                              float* __restrict__ wpool, float* __restrict__ mean) {
    int b = blockIdx.x;
    int tid = threadIdx.x;
    int wave = tid >> 6, lane = tid & 63;
    __shared__ float qk_s[300];
    __shared__ float sc[50];
    if (tid < 300) qk_s[tid] = qk[b * 300 + tid];
    __syncthreads();
    for (int k = wave; k < 50; k += 5) {
        const __hip_bfloat16* hp = h + (long)(b * 50 + k) * LDK;
        float partial = 0.f;
        #pragma unroll
        for (int i = 0; i < 5; ++i) {
            int j = lane + i * 64;
            if (j < 300) partial += __bfloat162float(hp[j]) * qk_s[j];
        }
        #pragma unroll
        for (int s = 32; s > 0; s >>= 1) partial += __shfl_xor(partial, s, 64);
        if (lane == 0) sc[k] = partial * (1.f / 16.f);
    }
    __syncthreads();
    if (tid == 0) {
        float mx = sc[0];
        for (int k = 1; k < 50; ++k) mx = fmaxf(mx, sc[k]);
        float s = 0.f;
        for (int k = 0; k < 50; ++k) { float e = __expf(sc[k] - mx); sc[k] = e; s += e; }
        float inv = 1.f / s;
        for (int k = 0; k < 50; ++k) sc[k] *= inv;
    }
    __syncthreads();
    if (tid < 300) {
        float aw = 0.f, am = 0.f;
        for (int k = 0; k < 50; ++k) {
            float v = __bfloat162float(h[(long)(b * 50 + k) * LDK + tid]);
            aw += sc[k] * v;
            am += v;
        }
        wpool[b * 300 + tid] = aw;
        mean[b * 300 + tid]  = am * (1.f / 50.f);
    }
}

// ---------------- head (coalesced via transposed weights) ----------------
__global__ __launch_bounds__(512) void k_head(const float* __restrict__ wpool, const float* __restrict__ mean,
                                              const float* __restrict__ metal2,
                                              const float* __restrict__ wvT, const float* __restrict__ lgwT,
                                              const float* __restrict__ lgb,
                                              const float* __restrict__ ph1wT, const float* __restrict__ ph1b,
                                              const float* __restrict__ ph2w, const float* __restrict__ ph2b,
                                              float* __restrict__ out) {
    int b = blockIdx.x;
    int tid = threadIdx.x;
    __shared__ float wp_s[300], mn_s[300], f_s[256], red[512];
    if (tid < 300) { wp_s[tid] = wpool[b * 300 + tid]; mn_s[tid] = mean[b * 300 + tid]; }
    __syncthreads();
    if (tid < 256) {
        float att = 0.f, lg = 0.f;
        #pragma unroll 4
        for (int k = 0; k < 300; ++k) {
            att += wp_s[k] * wvT[k * 256 + tid];
            lg  += mn_s[k] * lgwT[k * 256 + tid];
        }
        lg = fmaxf(lg + lgb[tid], 0.f);
        f_s[tid] = fmaxf(att, 0.f) + metal2[b * 256 + tid] + lg;
    }
    __syncthreads();
    float a = ph1b[tid];
    #pragma unroll 8
    for (int k = 0; k < 256; ++k) a += f_s[k] * ph1wT[k * 512 + tid];
    float sp = fmaxf(a, 0.f) + log1pf(__expf(-fabsf(a)));   // stable softplus
    red[tid] = sp * ph2w[tid];
    __syncthreads();
    for (int s = 256; s > 0; s >>= 1) {
        if (tid < s) red[tid] += red[tid + s];
        __syncthreads();
    }
    if (tid == 0) out[b] = red[0] + ph2b[0];
}

extern "C" void kernel_launch(void* const* d_in, const int* in_sizes, int n_in,
                              void* d_out, int out_size, void* d_ws, size_t ws_size,
                              hipStream_t stream) {
    const int*   x_type   = (const int*)d_in[0];
    const float* x_feat   = (const float*)d_in[1];
    const int*   eindex   = (const int*)d_in[2];
    const float* eattr    = (const float*)d_in[3];
    const int*   mtype    = (const int*)d_in[4];
    const float* mfeat    = (const float*)d_in[5];
    const float* x_emb    = (const float*)d_in[6];
    const float* x_weight = (const float*)d_in[7];
    const float* ew1      = (const float*)d_in[8];
    const float* mlp_w    = (const float*)d_in[9];
    const float* mlp_b    = (const float*)d_in[10];
    const float* bn_g     = (const float*)d_in[11];
    const float* bn_b     = (const float*)d_in[12];
    const float* bn_rm    = (const float*)d_in[13];
    const float* bn_rv    = (const float*)d_in[14];
    const float* me1_w    = (const float*)d_in[15];
    const float* me1_b    = (const float*)d_in[16];
    const float* me2      = (const float*)d_in[17];
    const float* wq       = (const float*)d_in[18];
    const float* wk       = (const float*)d_in[19];
    const float* wv       = (const float*)d_in[20];
    const float* ml_w     = (const float*)d_in[21];
    const float* ml_b     = (const float*)d_in[22];
    const float* lg_w     = (const float*)d_in[23];
    const float* lg_b     = (const float*)d_in[24];
    const float* ph1_w    = (const float*)d_in[25];
    const float* ph1_b    = (const float*)d_in[26];
    const float* ph2_w    = (const float*)d_in[27];
    const float* ph2_b    = (const float*)d_in[28];

    char* ws = (char*)d_ws;
    size_t o = 0;
    auto alloc = [&](size_t bytes) -> void* {
        void* p = ws + o;
        o += (bytes + 255) & ~(size_t)255;
        return p;
    };
    __hip_bfloat16* h    = (__hip_bfloat16*)alloc((size_t)MPAD * LDK * 2);
    float*          mh   = (float*)alloc((size_t)MPAD * LDK * 4);
    __hip_bfloat16* wb   = (__hip_bfloat16*)alloc((size_t)5 * 320 * 320 * 2);
    int*     cnt    = (int*)alloc((size_t)NNODES * 4);
    int*     offs   = (int*)alloc((size_t)(NNODES + 1) * 4);
    int*     cur    = (int*)alloc((size_t)NNODES * 4);
    int*     bsum   = (int*)alloc((size_t)64 * 4);
    EdgeRec* pack   = (EdgeRec*)alloc((size_t)NTOT * sizeof(EdgeRec));
    float*   prm    = (float*)alloc(1520 * 4);
    float*   metal2 = (float*)alloc((size_t)1000 * 256 * 4);
    float*   qk     = (float*)alloc((size_t)1000 * 300 * 4);
    float*   wpool  = (float*)alloc((size_t)1000 * 300 * 4);
    float*   meanp  = (float*)alloc((size_t)1000 * 300 * 4);
    float*   wqT    = (float*)alloc((size_t)300 * 256 * 4);
    float*   mlwT   = (float*)alloc((size_t)300 * 256 * 4);
    float*   wvT    = (float*)alloc((size_t)300 * 256 * 4);
    float*   lgwT   = (float*)alloc((size_t)300 * 256 * 4);
    float*   ph1wT  = (float*)alloc((size_t)256 * 512 * 4);
    float*   me1wT  = (float*)alloc((size_t)17 * 300 * 4);
    (void)ws_size; (void)in_sizes; (void)n_in; (void)out_size;

    hipMemsetAsync(cnt, 0, (size_t)NNODES * 4, stream);
    hipMemsetAsync(cur, 0, (size_t)NNODES * 4, stream);

    k_cvt<<<(5 * 320 * 320 + 255) / 256, 256, 0, stream>>>(mlp_w, wb);
    k_tr<<<(256 * 300 + 255) / 256, 256, 0, stream>>>(wq, wqT, 256, 300);
    k_tr<<<(256 * 300 + 255) / 256, 256, 0, stream>>>(ml_w, mlwT, 256, 300);
    k_tr<<<(256 * 300 + 255) / 256, 256, 0, stream>>>(wv, wvT, 256, 300);
    k_tr<<<(256 * 300 + 255) / 256, 256, 0, stream>>>(lg_w, lgwT, 256, 300);
    k_tr<<<(512 * 256 + 255) / 256, 256, 0, stream>>>(ph1_w, ph1wT, 512, 256);
    k_tr<<<(300 * 17 + 255) / 256, 256, 0, stream>>>(me1_w, me1wT, 300, 17);
    k_init<<<NNODES, 320, 0, stream>>>(x_type, x_feat, x_emb, x_weight, h);
    k_count<<<(NTOT + 255) / 256, 256, 0, stream>>>(eindex, cnt);
    k_scan1<<<NSCAN, 1024, 0, stream>>>(cnt, offs, bsum);
    k_scan2<<<1, 64, 0, stream>>>(bsum);
    k_scan3<<<NSCAN, 1024, 0, stream>>>(offs, bsum);
    k_fill<<<(NTOT + 255) / 256, 256, 0, stream>>>(eindex, eattr, offs, cur, pack);

    for (int l = 0; l < NLAYERS; ++l) {
        k_prep<<<1, 320, 0, stream>>>(mlp_w + (size_t)l * 90000, ew1 + l * 600, mlp_b + l * 300,
                                      bn_g + l * 300, bn_b + l * 300, bn_rm + l * 300,
                                      bn_rv + l * 300, prm);
        dim3 g(MPAD / 128, 5);
        k_gemm<<<g, 256, 0, stream>>>(h, wb + (size_t)l * 102400, mh);
        k_aggr<<<(NNODES + 3) / 4, 256, 0, stream>>>(mh, pack, offs, prm, h, (l < NLAYERS - 1) ? 1 : 0);
    }

    k_metal<<<1000, 320, 0, stream>>>(mtype, mfeat, me1wT, me1_b, me2, wqT, wk, mlwT, ml_b, metal2, qk);
    k_pool<<<1000, 320, 0, stream>>>(h, qk, wpool, meanp);
    k_head<<<1000, 512, 0, stream>>>(wpool, meanp, metal2, wvT, lgwT, lg_b,
                                     ph1wT, ph1_b, ph2_w, ph2_b, (float*)d_out);
}

// Round 5
// 741.831 us; speedup vs baseline: 2.2488x; 1.1488x over previous
//
#include <hip/hip_runtime.h>
#include <hip/hip_bf16.h>
#include <math.h>

#define NNODES  50000
#define NEDGES  200000
#define NTOT    250000      // E + N self loops
#define EMB     300
#define LDK     320         // padded K stride (bf16 h / mh / weights)
#define MPAD    50048       // 391 * 128 (GEMM M padding)
#define NLAYERS 5
#define NSCAN   49          // ceil(NNODES / 1024)

struct EdgeRec { int r; float c0, c1; };

typedef __attribute__((ext_vector_type(8))) short short8;
typedef __attribute__((ext_vector_type(4))) short short4v;
typedef __attribute__((ext_vector_type(4))) float floatx4;

__device__ inline void gll16(const void* g, void* s) {
    __builtin_amdgcn_global_load_lds((const __attribute__((address_space(1))) unsigned*)g,
                                     (__attribute__((address_space(3))) unsigned*)s, 16, 0, 0);
}

// ---------------- merged transposes for readout weights ----------------
__global__ void k_trall(const float* __restrict__ wq, const float* __restrict__ ml_w,
                        const float* __restrict__ wv, const float* __restrict__ lg_w,
                        const float* __restrict__ ph1_w, const float* __restrict__ me1_w,
                        float* __restrict__ wqT, float* __restrict__ mlwT,
                        float* __restrict__ wvT, float* __restrict__ lgwT,
                        float* __restrict__ ph1wT, float* __restrict__ me1wT) {
    int idx = blockIdx.x * 256 + threadIdx.x;
    if (idx < 76800) { int r = idx / 300, c = idx % 300; wqT[c * 256 + r] = wq[idx]; return; }
    idx -= 76800;
    if (idx < 76800) { int r = idx / 300, c = idx % 300; mlwT[c * 256 + r] = ml_w[idx]; return; }
    idx -= 76800;
    if (idx < 76800) { int r = idx / 300, c = idx % 300; wvT[c * 256 + r] = wv[idx]; return; }
    idx -= 76800;
    if (idx < 76800) { int r = idx / 300, c = idx % 300; lgwT[c * 256 + r] = lg_w[idx]; return; }
    idx -= 76800;
    if (idx < 131072) { int r = idx / 256, c = idx % 256; ph1wT[c * 512 + r] = ph1_w[idx]; return; }
    idx -= 131072;
    if (idx < 5100) { int r = idx / 17, c = idx % 17; me1wT[c * 300 + r] = me1_w[idx]; }
}

// ---------------- weight convert: wb[l][320][320] = bf16(mlp_w[l][300][300]) zero-padded ----------------
__global__ void k_cvt(const float* __restrict__ w, __hip_bfloat16* __restrict__ wb) {
    int idx = blockIdx.x * 256 + threadIdx.x;
    if (idx >= 5 * 320 * 320) return;
    int l = idx / 102400, r = idx % 102400, n = r / 320, k = r % 320;
    float v = (n < 300 && k < 300) ? w[l * 90000 + n * 300 + k] : 0.f;
    wb[idx] = __float2bfloat16(v);
}

// ---------------- node init: h = bf16(x_emb[x_type] + x_feat @ x_weight), 8 cols/thread ----------------
__global__ __launch_bounds__(256) void k_init(const int* __restrict__ xt,
                                              const float* __restrict__ xf,
                                              const float* __restrict__ xemb,
                                              const float* __restrict__ xw,
                                              __hip_bfloat16* __restrict__ h) {
    int gid = blockIdx.x * 256 + threadIdx.x;
    if (gid >= NNODES * 38) return;
    int n = gid / 38, c = (gid % 38) * 8;     // c in {0,8,...,296}
    bool full = (c <= 292);                   // c+8 <= 300 (only c=296 is partial: 4 valid)
    const float* er = xemb + (size_t)xt[n] * 300 + c;
    float v[8];
    float4 e0 = *(const float4*)er;
    v[0] = e0.x; v[1] = e0.y; v[2] = e0.z; v[3] = e0.w;
    if (full) { float4 e1 = *(const float4*)(er + 4); v[4] = e1.x; v[5] = e1.y; v[6] = e1.z; v[7] = e1.w; }
    else      { v[4] = v[5] = v[6] = v[7] = 0.f; }
    float fs[16];
    const float4* xf4 = (const float4*)(xf + n * 16);
    #pragma unroll
    for (int q = 0; q < 4; ++q) {
        float4 t = xf4[q];
        fs[4 * q] = t.x; fs[4 * q + 1] = t.y; fs[4 * q + 2] = t.z; fs[4 * q + 3] = t.w;
    }
    #pragma unroll
    for (int k = 0; k < 16; ++k) {
        const float* wr = xw + k * 300 + c;
        float4 w0 = *(const float4*)wr;
        v[0] += fs[k] * w0.x; v[1] += fs[k] * w0.y; v[2] += fs[k] * w0.z; v[3] += fs[k] * w0.w;
        if (full) {
            float4 w1 = *(const float4*)(wr + 4);
            v[4] += fs[k] * w1.x; v[5] += fs[k] * w1.y; v[6] += fs[k] * w1.z; v[7] += fs[k] * w1.w;
        }
    }
    alignas(16) __hip_bfloat16 ob[8];
    #pragma unroll
    for (int i = 0; i < 8; ++i) ob[i] = __float2bfloat16(v[i]);
    __hip_bfloat16* hp = h + (size_t)n * LDK + c;
    if (full) *(short8*)hp  = *(const short8*)ob;
    else      *(short4v*)hp = *(const short4v*)ob;   // cols 296..299
    // pad cols 300..319 left unwritten: B k-pad is zero so they never contribute
}

// ---------------- CSR build ----------------
__global__ void k_count(const int* __restrict__ ei, int* __restrict__ cnt) {
    int e = blockIdx.x * blockDim.x + threadIdx.x;
    if (e >= NTOT) return;
    int c = (e < NEDGES) ? ei[NEDGES + e] : (e - NEDGES);
    atomicAdd(&cnt[c], 1);
}

__global__ __launch_bounds__(1024) void k_scan1(const int* __restrict__ cnt, int* __restrict__ off,
                                                int* __restrict__ bsum) {
    int tid = threadIdx.x;
    int gid = blockIdx.x * 1024 + tid;
    int lane = tid & 63, wv = tid >> 6;
    int v = (gid < NNODES) ? cnt[gid] : 0;
    int x = v;
    #pragma unroll
    for (int s = 1; s < 64; s <<= 1) {
        int t = __shfl_up(x, s, 64);
        if (lane >= s) x += t;
    }
    __shared__ int wsum[16];
    if (lane == 63) wsum[wv] = x;
    __syncthreads();
    if (wv == 0) {
        int w = (lane < 16) ? wsum[lane] : 0;
        #pragma unroll
        for (int s = 1; s < 16; s <<= 1) {
            int t = __shfl_up(w, s, 64);
            if (lane >= s) w += t;
        }
        if (lane < 16) wsum[lane] = w;
    }
    __syncthreads();
    int base = (wv > 0) ? wsum[wv - 1] : 0;
    int incl = x + base;
    if (gid < NNODES) off[gid] = incl - v;
    if (tid == 1023) bsum[blockIdx.x] = incl;
}

__global__ __launch_bounds__(64) void k_scan2(int* __restrict__ bsum) {
    int lane = threadIdx.x;
    int v = (lane < NSCAN) ? bsum[lane] : 0;
    int x = v;
    #pragma unroll
    for (int s = 1; s < 64; s <<= 1) {
        int t = __shfl_up(x, s, 64);
        if (lane >= s) x += t;
    }
    if (lane < NSCAN) bsum[lane] = x - v;
}

__global__ __launch_bounds__(1024) void k_scan3(int* __restrict__ off, const int* __restrict__ bsum) {
    int gid = blockIdx.x * 1024 + threadIdx.x;
    if (gid < NNODES) off[gid] += bsum[blockIdx.x];
    if (gid == 0) off[NNODES] = NTOT;
}

__global__ void k_fill(const int* __restrict__ ei, const float* __restrict__ ea,
                       const int* __restrict__ off, int* __restrict__ cur,
                       EdgeRec* __restrict__ pack) {
    int e = blockIdx.x * blockDim.x + threadIdx.x;
    if (e >= NTOT) return;
    int r, c; float c0, c1;
    if (e < NEDGES) { r = ei[e]; c = ei[NEDGES + e]; c0 = ea[2 * e]; c1 = ea[2 * e + 1]; }
    else            { r = c = e - NEDGES; c0 = 0.f; c1 = 4.f; }
    int p = atomicAdd(&cur[c], 1);
    EdgeRec rec; rec.r = r; rec.c0 = c0; rec.c1 = c1;
    pack[off[c] + p] = rec;
}

// ---------------- per-layer precompute, all layers in one launch, coalesced ----------------
// block (j, l): wave computes u0[j]=dot(W[l][j,:],ew[l][0]), u1 likewise, + bias/BN constants
__global__ __launch_bounds__(64) void k_prep(const float* __restrict__ mlp_w, const float* __restrict__ ew1,
                                             const float* __restrict__ mlp_b, const float* __restrict__ bn_g,
                                             const float* __restrict__ bn_b, const float* __restrict__ bn_rm,
                                             const float* __restrict__ bn_rv, float* __restrict__ prm) {
    int j = blockIdx.x, l = blockIdx.y;
    int lane = threadIdx.x;
    const float* W  = mlp_w + (size_t)l * 90000 + (size_t)j * 300;
    const float* ew = ew1 + l * 600;
    float a0 = 0.f, a1 = 0.f;
    #pragma unroll
    for (int i = 0; i < 5; ++i) {
        int k = lane + i * 64;
        if (k < 300) {
            float w = W[k];
            a0 += w * ew[k];
            a1 += w * ew[300 + k];
        }
    }
    #pragma unroll
    for (int s = 32; s > 0; s >>= 1) { a0 += __shfl_xor(a0, s, 64); a1 += __shfl_xor(a1, s, 64); }
    if (lane == 0) {
        float* p = prm + l * 1520;
        p[j] = a0;
        p[304 + j] = a1;
        p[608 + j] = mlp_b[l * 300 + j];
        float sc = bn_g[l * 300 + j] * rsqrtf(bn_rv[l * 300 + j] + 1e-5f);
        p[912 + j] = sc;
        p[1216 + j] = bn_b[l * 300 + j] - bn_rm[l * 300 + j] * sc;
    }
}

// ---------------- MFMA GEMM: C[M,320] = A[M,320] @ B[320,320]^T, bf16 in / bf16 out ----------------
__global__ __launch_bounds__(256) void k_gemm(const __hip_bfloat16* __restrict__ A,
                                              const __hip_bfloat16* __restrict__ B,
                                              __hip_bfloat16* __restrict__ C) {
    __shared__ __hip_bfloat16 As[128 * 32];
    __shared__ __hip_bfloat16 Bs[64 * 32];
    int tid = threadIdx.x;
    int lane = tid & 63, w = tid >> 6;
    int row0 = blockIdx.x * 128, col0 = blockIdx.y * 64;

    floatx4 acc[2][4];
    #pragma unroll
    for (int i = 0; i < 2; ++i)
        #pragma unroll
        for (int j = 0; j < 4; ++j) acc[i][j] = (floatx4){0.f, 0.f, 0.f, 0.f};

    const __hip_bfloat16* ga0 = A + (size_t)(row0 + w * 32 + (lane >> 2)) * LDK + (lane & 3) * 8;
    const __hip_bfloat16* ga1 = ga0 + (size_t)16 * LDK;
    const __hip_bfloat16* gb  = B + (size_t)(col0 + w * 16 + (lane >> 2)) * LDK + (lane & 3) * 8;
    __hip_bfloat16* sa0 = &As[(w * 32) * 32];
    __hip_bfloat16* sa1 = &As[(w * 32 + 16) * 32];
    __hip_bfloat16* sb  = &Bs[(w * 16) * 32];

    int m15 = lane & 15, kof = (lane >> 4) * 8;

    for (int k0 = 0; k0 < LDK; k0 += 32) {
        __syncthreads();
        gll16(ga0 + k0, sa0);
        gll16(ga1 + k0, sa1);
        gll16(gb  + k0, sb);
        __syncthreads();

        short8 a[2], b[4];
        a[0] = *(const short8*)&As[(w * 32 +      m15) * 32 + kof];
        a[1] = *(const short8*)&As[(w * 32 + 16 + m15) * 32 + kof];
        #pragma unroll
        for (int nt = 0; nt < 4; ++nt)
            b[nt] = *(const short8*)&Bs[(nt * 16 + m15) * 32 + kof];

        #pragma unroll
        for (int mt = 0; mt < 2; ++mt)
            #pragma unroll
            for (int nt = 0; nt < 4; ++nt)
                acc[mt][nt] = __builtin_amdgcn_mfma_f32_16x16x32_bf16(a[mt], b[nt], acc[mt][nt], 0, 0, 0);
    }

    int rbase = row0 + w * 32 + (lane >> 4) * 4;
    #pragma unroll
    for (int mt = 0; mt < 2; ++mt)
        #pragma unroll
        for (int i = 0; i < 4; ++i) {
            long gr = rbase + mt * 16 + i;
            #pragma unroll
            for (int nt = 0; nt < 4; ++nt)
                C[gr * LDK + col0 + nt * 16 + m15] = __float2bfloat16(acc[mt][nt][i]);
        }
}

// ---------------- aggregate: h[n] = bf16(BN( sum relu(mh[row]+c0*u0+c1*u1+b) )), wave/node, bf16x2 lanes ----------------
__global__ __launch_bounds__(256) void k_aggr(const __hip_bfloat16* __restrict__ mh,
                                              const EdgeRec* __restrict__ pack,
                                              const int* __restrict__ off, const float* __restrict__ prm,
                                              __hip_bfloat16* __restrict__ h, int do_relu) {
    int wave = threadIdx.x >> 6;
    int lane = threadIdx.x & 63;
    int n = blockIdx.x * 4 + wave;
    if (n >= NNODES) return;
    float u0[3][2], u1[3][2], bv[3][2], sc[3][2], sh[3][2], acc[3][2];
    #pragma unroll
    for (int i = 0; i < 3; ++i) {
        int j = 2 * lane + 128 * i;
        #pragma unroll
        for (int t = 0; t < 2; ++t) {
            bool ok = (j + t) < 300;
            u0[i][t] = ok ? prm[j + t]        : 0.f;
            u1[i][t] = ok ? prm[304 + j + t]  : 0.f;
            bv[i][t] = ok ? prm[608 + j + t]  : 0.f;
            sc[i][t] = ok ? prm[912 + j + t]  : 0.f;
            sh[i][t] = ok ? prm[1216 + j + t] : 0.f;
            acc[i][t] = 0.f;
        }
    }
    int p0 = off[n], p1 = off[n + 1];
    for (int p = p0; p < p1; ++p) {
        EdgeRec rec = pack[p];
        const __hip_bfloat16* base = mh + (size_t)rec.r * LDK;
        #pragma unroll
        for (int i = 0; i < 3; ++i) {
            int j = 2 * lane + 128 * i;
            if (j < 300) {
                __hip_bfloat162 hv = *(const __hip_bfloat162*)&base[j];
                float v0 = __bfloat162float(hv.x) + rec.c0 * u0[i][0] + rec.c1 * u1[i][0] + bv[i][0];
                float v1 = __bfloat162float(hv.y) + rec.c0 * u0[i][1] + rec.c1 * u1[i][1] + bv[i][1];
                acc[i][0] += fmaxf(v0, 0.f);
                acc[i][1] += fmaxf(v1, 0.f);
            }
        }
    }
    #pragma unroll
    for (int i = 0; i < 3; ++i) {
        int j = 2 * lane + 128 * i;
        if (j < 300) {
            float v0 = acc[i][0] * sc[i][0] + sh[i][0];
            float v1 = acc[i][1] * sc[i][1] + sh[i][1];
            if (do_relu) { v0 = fmaxf(v0, 0.f); v1 = fmaxf(v1, 0.f); }
            __hip_bfloat162 o;
            o.x = __float2bfloat16(v0);
            o.y = __float2bfloat16(v1);
            *(__hip_bfloat162*)&h[(size_t)n * LDK + j] = o;
        }
    }
}

// ---------------- metal branch (coalesced via transposed weights) ----------------
__global__ __launch_bounds__(320) void k_metal(const int* __restrict__ mt, const float* __restrict__ mfeat,
                                               const float* __restrict__ me1wT, const float* __restrict__ me1b,
                                               const float* __restrict__ me2,
                                               const float* __restrict__ wqT, const float* __restrict__ wk,
                                               const float* __restrict__ mlwT, const float* __restrict__ mlb,
                                               float* __restrict__ metal2, float* __restrict__ qk) {
    int b = blockIdx.x;
    int tid = threadIdx.x;
    __shared__ float fs[17];
    __shared__ float mf_s[300];
    __shared__ float q_s[256];
    if (tid < 17) fs[tid] = mfeat[b * 17 + tid];
    __syncthreads();
    if (tid < 300) {
        float v = me1b[tid] + me2[mt[b] * 300 + tid];
        #pragma unroll
        for (int k = 0; k < 17; ++k) v += fs[k] * me1wT[k * 300 + tid];
        mf_s[tid] = v;
    }
    __syncthreads();
    if (tid < 256) {
        float q = 0.f, m2 = 0.f;
        #pragma unroll 4
        for (int k = 0; k < 300; ++k) {
            float m = mf_s[k];
            q  += m * wqT[k * 256 + tid];
            m2 += m * mlwT[k * 256 + tid];
        }
        q_s[tid] = q;
        metal2[b * 256 + tid] = fmaxf(m2 + mlb[tid], 0.f);
    }
    __syncthreads();
    if (tid < 300) {
        float a = 0.f;
        #pragma unroll 4
        for (int j = 0; j < 256; ++j) a += q_s[j] * wk[j * 300 + tid];
        qk[b * 300 + tid] = a;
    }
}

// ---------------- attention pool ----------------
__global__ __launch_bounds__(320) void k_pool(const __hip_bfloat16* __restrict__ h, const float* __restrict__ qk,
                                              float* __restrict__ wpool, float* __restrict__ mean) {
    int b = blockIdx.x;
    int tid = threadIdx.x;
    int wave = tid >> 6, lane = tid & 63;
    __shared__ float qk_s[300];
    __shared__ float sc[50];
    if (tid < 300) qk_s[tid] = qk[b * 300 + tid];
    __syncthreads();
    for (int k = wave; k < 50; k += 5) {
        const __hip_bfloat16* hp = h + (long)(b * 50 + k) * LDK;
        float partial = 0.f;
        #pragma unroll
        for (int i = 0; i < 5; ++i) {
            int j = lane + i * 64;
            if (j < 300) partial += __bfloat162float(hp[j]) * qk_s[j];
        }
        #pragma unroll
        for (int s = 32; s > 0; s >>= 1) partial += __shfl_xor(partial, s, 64);
        if (lane == 0) sc[k] = partial * (1.f / 16.f);
    }
    __syncthreads();
    if (tid == 0) {
        float mx = sc[0];
        for (int k = 1; k < 50; ++k) mx = fmaxf(mx, sc[k]);
        float s = 0.f;
        for (int k = 0; k < 50; ++k) { float e = __expf(sc[k] - mx); sc[k] = e; s += e; }
        float inv = 1.f / s;
        for (int k = 0; k < 50; ++k) sc[k] *= inv;
    }
    __syncthreads();
    if (tid < 300) {
        float aw = 0.f, am = 0.f;
        for (int k = 0; k < 50; ++k) {
            float v = __bfloat162float(h[(long)(b * 50 + k) * LDK + tid]);
            aw += sc[k] * v;
            am += v;
        }
        wpool[b * 300 + tid] = aw;
        mean[b * 300 + tid]  = am * (1.f / 50.f);
    }
}

// ---------------- head (coalesced via transposed weights) ----------------
__global__ __launch_bounds__(512) void k_head(const float* __restrict__ wpool, const float* __restrict__ mean,
                                              const float* __restrict__ metal2,
                                              const float* __restrict__ wvT, const float* __restrict__ lgwT,
                                              const float* __restrict__ lgb,
                                              const float* __restrict__ ph1wT, const float* __restrict__ ph1b,
                                              const float* __restrict__ ph2w, const float* __restrict__ ph2b,
                                              float* __restrict__ out) {
    int b = blockIdx.x;
    int tid = threadIdx.x;
    __shared__ float wp_s[300], mn_s[300], f_s[256], red[512];
    if (tid < 300) { wp_s[tid] = wpool[b * 300 + tid]; mn_s[tid] = mean[b * 300 + tid]; }
    __syncthreads();
    if (tid < 256) {
        float att = 0.f, lg = 0.f;
        #pragma unroll 4
        for (int k = 0; k < 300; ++k) {
            att += wp_s[k] * wvT[k * 256 + tid];
            lg  += mn_s[k] * lgwT[k * 256 + tid];
        }
        lg = fmaxf(lg + lgb[tid], 0.f);
        f_s[tid] = fmaxf(att, 0.f) + metal2[b * 256 + tid] + lg;
    }
    __syncthreads();
    float a = ph1b[tid];
    #pragma unroll 8
    for (int k = 0; k < 256; ++k) a += f_s[k] * ph1wT[k * 512 + tid];
    float sp = fmaxf(a, 0.f) + log1pf(__expf(-fabsf(a)));   // stable softplus
    red[tid] = sp * ph2w[tid];
    __syncthreads();
    for (int s = 256; s > 0; s >>= 1) {
        if (tid < s) red[tid] += red[tid + s];
        __syncthreads();
    }
    if (tid == 0) out[b] = red[0] + ph2b[0];
}

extern "C" void kernel_launch(void* const* d_in, const int* in_sizes, int n_in,
                              void* d_out, int out_size, void* d_ws, size_t ws_size,
                              hipStream_t stream) {
    const int*   x_type   = (const int*)d_in[0];
    const float* x_feat   = (const float*)d_in[1];
    const int*   eindex   = (const int*)d_in[2];
    const float* eattr    = (const float*)d_in[3];
    const int*   mtype    = (const int*)d_in[4];
    const float* mfeat    = (const float*)d_in[5];
    const float* x_emb    = (const float*)d_in[6];
    const float* x_weight = (const float*)d_in[7];
    const float* ew1      = (const float*)d_in[8];
    const float* mlp_w    = (const float*)d_in[9];
    const float* mlp_b    = (const float*)d_in[10];
    const float* bn_g     = (const float*)d_in[11];
    const float* bn_b     = (const float*)d_in[12];
    const float* bn_rm    = (const float*)d_in[13];
    const float* bn_rv    = (const float*)d_in[14];
    const float* me1_w    = (const float*)d_in[15];
    const float* me1_b    = (const float*)d_in[16];
    const float* me2      = (const float*)d_in[17];
    const float* wq       = (const float*)d_in[18];
    const float* wk       = (const float*)d_in[19];
    const float* wv       = (const float*)d_in[20];
    const float* ml_w     = (const float*)d_in[21];
    const float* ml_b     = (const float*)d_in[22];
    const float* lg_w     = (const float*)d_in[23];
    const float* lg_b     = (const float*)d_in[24];
    const float* ph1_w    = (const float*)d_in[25];
    const float* ph1_b    = (const float*)d_in[26];
    const float* ph2_w    = (const float*)d_in[27];
    const float* ph2_b    = (const float*)d_in[28];

    char* ws = (char*)d_ws;
    size_t o = 0;
    auto alloc = [&](size_t bytes) -> void* {
        void* p = ws + o;
        o += (bytes + 255) & ~(size_t)255;
        return p;
    };
    __hip_bfloat16* h    = (__hip_bfloat16*)alloc((size_t)MPAD * LDK * 2);
    __hip_bfloat16* mh   = (__hip_bfloat16*)alloc((size_t)MPAD * LDK * 2);
    __hip_bfloat16* wb   = (__hip_bfloat16*)alloc((size_t)5 * 320 * 320 * 2);
    int*     cnt    = (int*)alloc((size_t)NNODES * 4);
    int*     offs   = (int*)alloc((size_t)(NNODES + 1) * 4);
    int*     cur    = (int*)alloc((size_t)NNODES * 4);
    int*     bsum   = (int*)alloc((size_t)64 * 4);
    EdgeRec* pack   = (EdgeRec*)alloc((size_t)NTOT * sizeof(EdgeRec));
    float*   prm    = (float*)alloc((size_t)NLAYERS * 1520 * 4);
    float*   metal2 = (float*)alloc((size_t)1000 * 256 * 4);
    float*   qk     = (float*)alloc((size_t)1000 * 300 * 4);
    float*   wpool  = (float*)alloc((size_t)1000 * 300 * 4);
    float*   meanp  = (float*)alloc((size_t)1000 * 300 * 4);
    float*   wqT    = (float*)alloc((size_t)300 * 256 * 4);
    float*   mlwT   = (float*)alloc((size_t)300 * 256 * 4);
    float*   wvT    = (float*)alloc((size_t)300 * 256 * 4);
    float*   lgwT   = (float*)alloc((size_t)300 * 256 * 4);
    float*   ph1wT  = (float*)alloc((size_t)256 * 512 * 4);
    float*   me1wT  = (float*)alloc((size_t)17 * 300 * 4);
    (void)ws_size; (void)in_sizes; (void)n_in; (void)out_size;

    hipMemsetAsync(cnt, 0, (size_t)NNODES * 4, stream);
    hipMemsetAsync(cur, 0, (size_t)NNODES * 4, stream);

    k_cvt<<<(5 * 320 * 320 + 255) / 256, 256, 0, stream>>>(mlp_w, wb);
    k_trall<<<(443372 + 255) / 256, 256, 0, stream>>>(wq, ml_w, wv, lg_w, ph1_w, me1_w,
                                                      wqT, mlwT, wvT, lgwT, ph1wT, me1wT);
    k_init<<<(NNODES * 38 + 255) / 256, 256, 0, stream>>>(x_type, x_feat, x_emb, x_weight, h);
    k_count<<<(NTOT + 255) / 256, 256, 0, stream>>>(eindex, cnt);
    k_scan1<<<NSCAN, 1024, 0, stream>>>(cnt, offs, bsum);
    k_scan2<<<1, 64, 0, stream>>>(bsum);
    k_scan3<<<NSCAN, 1024, 0, stream>>>(offs, bsum);
    k_fill<<<(NTOT + 255) / 256, 256, 0, stream>>>(eindex, eattr, offs, cur, pack);
    {
        dim3 gp(300, NLAYERS);
        k_prep<<<gp, 64, 0, stream>>>(mlp_w, ew1, mlp_b, bn_g, bn_b, bn_rm, bn_rv, prm);
    }

    for (int l = 0; l < NLAYERS; ++l) {
        dim3 g(MPAD / 128, 5);
        k_gemm<<<g, 256, 0, stream>>>(h, wb + (size_t)l * 102400, mh);
        k_aggr<<<(NNODES + 3) / 4, 256, 0, stream>>>(mh, pack, offs, prm + (size_t)l * 1520, h,
                                                     (l < NLAYERS - 1) ? 1 : 0);
    }

    k_metal<<<1000, 320, 0, stream>>>(mtype, mfeat, me1wT, me1_b, me2, wqT, wk, mlwT, ml_b, metal2, qk);
    k_pool<<<1000, 320, 0, stream>>>(h, qk, wpool, meanp);
    k_head<<<1000, 512, 0, stream>>>(wpool, meanp, metal2, wvT, lgwT, lg_b,
                                     ph1wT, ph1_b, ph2_w, ph2_b, (float*)d_out);
}

// Round 6
// 727.290 us; speedup vs baseline: 2.2938x; 1.0200x over previous
//
#include <hip/hip_runtime.h>
#include <hip/hip_bf16.h>
#include <math.h>

#define NNODES  50000
#define NEDGES  200000
#define NTOT    250000      // E + N self loops
#define EMB     300
#define LDK     320         // padded K stride (bf16 h / mh / weights)
#define MPAD    50048       // 391 * 128 (GEMM M padding)
#define NLAYERS 5
#define NSCAN   49          // ceil(NNODES / 1024)
#define NB      4           // graphs per k_metal block

struct EdgeRec { int r; float c0, c1; };

typedef __attribute__((ext_vector_type(8))) short short8;
typedef __attribute__((ext_vector_type(4))) short short4v;
typedef __attribute__((ext_vector_type(4))) float floatx4;

__device__ inline void gll16(const void* g, void* s) {
    __builtin_amdgcn_global_load_lds((const __attribute__((address_space(1))) unsigned*)g,
                                     (__attribute__((address_space(3))) unsigned*)s, 16, 0, 0);
}

// ---------------- merged transposes for readout weights ----------------
__global__ void k_trall(const float* __restrict__ wq, const float* __restrict__ ml_w,
                        const float* __restrict__ wv, const float* __restrict__ lg_w,
                        const float* __restrict__ ph1_w, const float* __restrict__ me1_w,
                        float* __restrict__ wqT, float* __restrict__ mlwT,
                        float* __restrict__ wvT, float* __restrict__ lgwT,
                        float* __restrict__ ph1wT, float* __restrict__ me1wT) {
    int idx = blockIdx.x * 256 + threadIdx.x;
    if (idx < 76800) { int r = idx / 300, c = idx % 300; wqT[c * 256 + r] = wq[idx]; return; }
    idx -= 76800;
    if (idx < 76800) { int r = idx / 300, c = idx % 300; mlwT[c * 256 + r] = ml_w[idx]; return; }
    idx -= 76800;
    if (idx < 76800) { int r = idx / 300, c = idx % 300; wvT[c * 256 + r] = wv[idx]; return; }
    idx -= 76800;
    if (idx < 76800) { int r = idx / 300, c = idx % 300; lgwT[c * 256 + r] = lg_w[idx]; return; }
    idx -= 76800;
    if (idx < 131072) { int r = idx / 256, c = idx % 256; ph1wT[c * 512 + r] = ph1_w[idx]; return; }
    idx -= 131072;
    if (idx < 5100) { int r = idx / 17, c = idx % 17; me1wT[c * 300 + r] = me1_w[idx]; }
}

// ---------------- weight convert: wb[l][320][320] = bf16(mlp_w[l][300][300]) zero-padded ----------------
__global__ void k_cvt(const float* __restrict__ w, __hip_bfloat16* __restrict__ wb) {
    int idx = blockIdx.x * 256 + threadIdx.x;
    if (idx >= 5 * 320 * 320) return;
    int l = idx / 102400, r = idx % 102400, n = r / 320, k = r % 320;
    float v = (n < 300 && k < 300) ? w[l * 90000 + n * 300 + k] : 0.f;
    wb[idx] = __float2bfloat16(v);
}

// ---------------- node init: h = bf16(x_emb[x_type] + x_feat @ x_weight), 8 cols/thread ----------------
__global__ __launch_bounds__(256) void k_init(const int* __restrict__ xt,
                                              const float* __restrict__ xf,
                                              const float* __restrict__ xemb,
                                              const float* __restrict__ xw,
                                              __hip_bfloat16* __restrict__ h) {
    int gid = blockIdx.x * 256 + threadIdx.x;
    if (gid >= NNODES * 38) return;
    int n = gid / 38, c = (gid % 38) * 8;     // c in {0,8,...,296}
    bool full = (c <= 292);
    const float* er = xemb + (size_t)xt[n] * 300 + c;
    float v[8];
    float4 e0 = *(const float4*)er;
    v[0] = e0.x; v[1] = e0.y; v[2] = e0.z; v[3] = e0.w;
    if (full) { float4 e1 = *(const float4*)(er + 4); v[4] = e1.x; v[5] = e1.y; v[6] = e1.z; v[7] = e1.w; }
    else      { v[4] = v[5] = v[6] = v[7] = 0.f; }
    float fs[16];
    const float4* xf4 = (const float4*)(xf + n * 16);
    #pragma unroll
    for (int q = 0; q < 4; ++q) {
        float4 t = xf4[q];
        fs[4 * q] = t.x; fs[4 * q + 1] = t.y; fs[4 * q + 2] = t.z; fs[4 * q + 3] = t.w;
    }
    #pragma unroll
    for (int k = 0; k < 16; ++k) {
        const float* wr = xw + k * 300 + c;
        float4 w0 = *(const float4*)wr;
        v[0] += fs[k] * w0.x; v[1] += fs[k] * w0.y; v[2] += fs[k] * w0.z; v[3] += fs[k] * w0.w;
        if (full) {
            float4 w1 = *(const float4*)(wr + 4);
            v[4] += fs[k] * w1.x; v[5] += fs[k] * w1.y; v[6] += fs[k] * w1.z; v[7] += fs[k] * w1.w;
        }
    }
    alignas(16) __hip_bfloat16 ob[8];
    #pragma unroll
    for (int i = 0; i < 8; ++i) ob[i] = __float2bfloat16(v[i]);
    __hip_bfloat16* hp = h + (size_t)n * LDK + c;
    if (full) *(short8*)hp  = *(const short8*)ob;
    else      *(short4v*)hp = *(const short4v*)ob;
}

// ---------------- CSR build ----------------
__global__ void k_count(const int* __restrict__ ei, int* __restrict__ cnt) {
    int e = blockIdx.x * blockDim.x + threadIdx.x;
    if (e >= NTOT) return;
    int c = (e < NEDGES) ? ei[NEDGES + e] : (e - NEDGES);
    atomicAdd(&cnt[c], 1);
}

__global__ __launch_bounds__(1024) void k_scan1(const int* __restrict__ cnt, int* __restrict__ off,
                                                int* __restrict__ bsum) {
    int tid = threadIdx.x;
    int gid = blockIdx.x * 1024 + tid;
    int lane = tid & 63, wv = tid >> 6;
    int v = (gid < NNODES) ? cnt[gid] : 0;
    int x = v;
    #pragma unroll
    for (int s = 1; s < 64; s <<= 1) {
        int t = __shfl_up(x, s, 64);
        if (lane >= s) x += t;
    }
    __shared__ int wsum[16];
    if (lane == 63) wsum[wv] = x;
    __syncthreads();
    if (wv == 0) {
        int w = (lane < 16) ? wsum[lane] : 0;
        #pragma unroll
        for (int s = 1; s < 16; s <<= 1) {
            int t = __shfl_up(w, s, 64);
            if (lane >= s) w += t;
        }
        if (lane < 16) wsum[lane] = w;
    }
    __syncthreads();
    int base = (wv > 0) ? wsum[wv - 1] : 0;
    int incl = x + base;
    if (gid < NNODES) off[gid] = incl - v;
    if (tid == 1023) bsum[blockIdx.x] = incl;
}

__global__ __launch_bounds__(64) void k_scan2(int* __restrict__ bsum) {
    int lane = threadIdx.x;
    int v = (lane < NSCAN) ? bsum[lane] : 0;
    int x = v;
    #pragma unroll
    for (int s = 1; s < 64; s <<= 1) {
        int t = __shfl_up(x, s, 64);
        if (lane >= s) x += t;
    }
    if (lane < NSCAN) bsum[lane] = x - v;
}

__global__ __launch_bounds__(1024) void k_scan3(int* __restrict__ off, const int* __restrict__ bsum) {
    int gid = blockIdx.x * 1024 + threadIdx.x;
    if (gid < NNODES) off[gid] += bsum[blockIdx.x];
    if (gid == 0) off[NNODES] = NTOT;
}

__global__ void k_fill(const int* __restrict__ ei, const float* __restrict__ ea,
                       const int* __restrict__ off, int* __restrict__ cur,
                       EdgeRec* __restrict__ pack) {
    int e = blockIdx.x * blockDim.x + threadIdx.x;
    if (e >= NTOT) return;
    int r, c; float c0, c1;
    if (e < NEDGES) { r = ei[e]; c = ei[NEDGES + e]; c0 = ea[2 * e]; c1 = ea[2 * e + 1]; }
    else            { r = c = e - NEDGES; c0 = 0.f; c1 = 4.f; }
    int p = atomicAdd(&cur[c], 1);
    EdgeRec rec; rec.r = r; rec.c0 = c0; rec.c1 = c1;
    pack[off[c] + p] = rec;
}

// ---------------- per-layer precompute, all layers in one launch ----------------
__global__ __launch_bounds__(64) void k_prep(const float* __restrict__ mlp_w, const float* __restrict__ ew1,
                                             const float* __restrict__ mlp_b, const float* __restrict__ bn_g,
                                             const float* __restrict__ bn_b, const float* __restrict__ bn_rm,
                                             const float* __restrict__ bn_rv, float* __restrict__ prm) {
    int j = blockIdx.x, l = blockIdx.y;
    int lane = threadIdx.x;
    const float* W  = mlp_w + (size_t)l * 90000 + (size_t)j * 300;
    const float* ew = ew1 + l * 600;
    float a0 = 0.f, a1 = 0.f;
    #pragma unroll
    for (int i = 0; i < 5; ++i) {
        int k = lane + i * 64;
        if (k < 300) {
            float w = W[k];
            a0 += w * ew[k];
            a1 += w * ew[300 + k];
        }
    }
    #pragma unroll
    for (int s = 32; s > 0; s >>= 1) { a0 += __shfl_xor(a0, s, 64); a1 += __shfl_xor(a1, s, 64); }
    if (lane == 0) {
        float* p = prm + l * 1520;
        p[j] = a0;
        p[304 + j] = a1;
        p[608 + j] = mlp_b[l * 300 + j];
        float sc = bn_g[l * 300 + j] * rsqrtf(bn_rv[l * 300 + j] + 1e-5f);
        p[912 + j] = sc;
        p[1216 + j] = bn_b[l * 300 + j] - bn_rm[l * 300 + j] * sc;
    }
}

// ---------------- MFMA GEMM: C[M,320] = A[M,320] @ B[320,320]^T, bf16 in / bf16 out ----------------
// Block 128x160, 4 waves, wave = 32x160 (2 M-tiles x 10 N-tiles of 16x16x32 MFMA)
__global__ __launch_bounds__(256) void k_gemm(const __hip_bfloat16* __restrict__ A,
                                              const __hip_bfloat16* __restrict__ B,
                                              __hip_bfloat16* __restrict__ C) {
    __shared__ __hip_bfloat16 As[128 * 32];
    __shared__ __hip_bfloat16 Bs[160 * 32];
    int tid = threadIdx.x;
    int lane = tid & 63, w = tid >> 6;
    int row0 = blockIdx.x * 128, col0 = blockIdx.y * 160;

    floatx4 acc[2][10];
    #pragma unroll
    for (int i = 0; i < 2; ++i)
        #pragma unroll
        for (int j = 0; j < 10; ++j) acc[i][j] = (floatx4){0.f, 0.f, 0.f, 0.f};

    // A staging: each wave stages its 32 rows (2 x gll16 of 16 rows)
    const __hip_bfloat16* ga0 = A + (size_t)(row0 + w * 32 + (lane >> 2)) * LDK + (lane & 3) * 8;
    const __hip_bfloat16* ga1 = ga0 + (size_t)16 * LDK;
    __hip_bfloat16* sa0 = &As[(w * 32) * 32];
    __hip_bfloat16* sa1 = &As[(w * 32 + 16) * 32];
    // B staging: 160 rows -> waves 0,1 stage 48 rows (3x), waves 2,3 stage 32 rows (2x)
    int brow0 = (w < 2) ? w * 48 : 96 + (w - 2) * 32;
    int nb = (w < 2) ? 3 : 2;
    const __hip_bfloat16* gb = B + (size_t)(col0 + brow0 + (lane >> 2)) * LDK + (lane & 3) * 8;
    __hip_bfloat16* sb = &Bs[brow0 * 32];

    int m15 = lane & 15, kof = (lane >> 4) * 8;

    for (int k0 = 0; k0 < LDK; k0 += 32) {
        __syncthreads();
        gll16(ga0 + k0, sa0);
        gll16(ga1 + k0, sa1);
        for (int i = 0; i < nb; ++i)
            gll16(gb + (size_t)i * 16 * LDK + k0, sb + i * 16 * 32);
        __syncthreads();

        short8 a[2], b[10];
        a[0] = *(const short8*)&As[(w * 32 +      m15) * 32 + kof];
        a[1] = *(const short8*)&As[(w * 32 + 16 + m15) * 32 + kof];
        #pragma unroll
        for (int nt = 0; nt < 10; ++nt)
            b[nt] = *(const short8*)&Bs[(nt * 16 + m15) * 32 + kof];

        #pragma unroll
        for (int mt = 0; mt < 2; ++mt)
            #pragma unroll
            for (int nt = 0; nt < 10; ++nt)
                acc[mt][nt] = __builtin_amdgcn_mfma_f32_16x16x32_bf16(a[mt], b[nt], acc[mt][nt], 0, 0, 0);
    }

    int rbase = row0 + w * 32 + (lane >> 4) * 4;
    #pragma unroll
    for (int mt = 0; mt < 2; ++mt)
        #pragma unroll
        for (int i = 0; i < 4; ++i) {
            long gr = rbase + mt * 16 + i;
            #pragma unroll
            for (int nt = 0; nt < 10; ++nt)
                C[gr * LDK + col0 + nt * 16 + m15] = __float2bfloat16(acc[mt][nt][i]);
        }
}

// ---------------- aggregate: wave/node, 2-edge unroll for load-level parallelism ----------------
__global__ __launch_bounds__(256) void k_aggr(const __hip_bfloat16* __restrict__ mh,
                                              const EdgeRec* __restrict__ pack,
                                              const int* __restrict__ off, const float* __restrict__ prm,
                                              __hip_bfloat16* __restrict__ h, int do_relu) {
    int wave = threadIdx.x >> 6;
    int lane = threadIdx.x & 63;
    int n = blockIdx.x * 4 + wave;
    if (n >= NNODES) return;
    float u0[3][2], u1[3][2], bv[3][2], sc[3][2], sh[3][2], acc[3][2];
    #pragma unroll
    for (int i = 0; i < 3; ++i) {
        int j = 2 * lane + 128 * i;
        #pragma unroll
        for (int t = 0; t < 2; ++t) {
            bool ok = (j + t) < 300;
            u0[i][t] = ok ? prm[j + t]        : 0.f;
            u1[i][t] = ok ? prm[304 + j + t]  : 0.f;
            bv[i][t] = ok ? prm[608 + j + t]  : 0.f;
            sc[i][t] = ok ? prm[912 + j + t]  : 0.f;
            sh[i][t] = ok ? prm[1216 + j + t] : 0.f;
            acc[i][t] = 0.f;
        }
    }
    int p0 = off[n], p1 = off[n + 1];
    int p = p0;
    for (; p + 1 < p1; p += 2) {
        EdgeRec e0 = pack[p], e1 = pack[p + 1];
        const __hip_bfloat16* b0 = mh + (size_t)e0.r * LDK;
        const __hip_bfloat16* b1 = mh + (size_t)e1.r * LDK;
        __hip_bfloat162 hv0[3], hv1[3];
        #pragma unroll
        for (int i = 0; i < 3; ++i) {
            int j = 2 * lane + 128 * i;
            if (j < 300) {
                hv0[i] = *(const __hip_bfloat162*)&b0[j];
                hv1[i] = *(const __hip_bfloat162*)&b1[j];
            }
        }
        #pragma unroll
        for (int i = 0; i < 3; ++i) {
            int j = 2 * lane + 128 * i;
            if (j < 300) {
                acc[i][0] += fmaxf(__bfloat162float(hv0[i].x) + e0.c0 * u0[i][0] + e0.c1 * u1[i][0] + bv[i][0], 0.f);
                acc[i][1] += fmaxf(__bfloat162float(hv0[i].y) + e0.c0 * u0[i][1] + e0.c1 * u1[i][1] + bv[i][1], 0.f);
                acc[i][0] += fmaxf(__bfloat162float(hv1[i].x) + e1.c0 * u0[i][0] + e1.c1 * u1[i][0] + bv[i][0], 0.f);
                acc[i][1] += fmaxf(__bfloat162float(hv1[i].y) + e1.c0 * u0[i][1] + e1.c1 * u1[i][1] + bv[i][1], 0.f);
            }
        }
    }
    if (p < p1) {
        EdgeRec e0 = pack[p];
        const __hip_bfloat16* b0 = mh + (size_t)e0.r * LDK;
        #pragma unroll
        for (int i = 0; i < 3; ++i) {
            int j = 2 * lane + 128 * i;
            if (j < 300) {
                __hip_bfloat162 hv = *(const __hip_bfloat162*)&b0[j];
                acc[i][0] += fmaxf(__bfloat162float(hv.x) + e0.c0 * u0[i][0] + e0.c1 * u1[i][0] + bv[i][0], 0.f);
                acc[i][1] += fmaxf(__bfloat162float(hv.y) + e0.c0 * u0[i][1] + e0.c1 * u1[i][1] + bv[i][1], 0.f);
            }
        }
    }
    #pragma unroll
    for (int i = 0; i < 3; ++i) {
        int j = 2 * lane + 128 * i;
        if (j < 300) {
            float v0 = acc[i][0] * sc[i][0] + sh[i][0];
            float v1 = acc[i][1] * sc[i][1] + sh[i][1];
            if (do_relu) { v0 = fmaxf(v0, 0.f); v1 = fmaxf(v1, 0.f); }
            __hip_bfloat162 o;
            o.x = __float2bfloat16(v0);
            o.y = __float2bfloat16(v1);
            *(__hip_bfloat162*)&h[(size_t)n * LDK + j] = o;
        }
    }
}

// ---------------- metal branch: 4 graphs/block, weight streams amortized ----------------
__global__ __launch_bounds__(256) void k_metal(const int* __restrict__ mt, const float* __restrict__ mfeat,
                                               const float* __restrict__ me1wT, const float* __restrict__ me1b,
                                               const float* __restrict__ me2,
                                               const float* __restrict__ wqT, const float* __restrict__ wk,
                                               const float* __restrict__ mlwT, const float* __restrict__ mlb,
                                               float* __restrict__ metal2, float* __restrict__ qk) {
    int b0 = blockIdx.x * NB;
    int tid = threadIdx.x;
    __shared__ float fs[NB][17];
    __shared__ float mf_s[NB][300];
    __shared__ float q_s[NB][256];
    if (tid < NB * 17) fs[tid / 17][tid % 17] = mfeat[b0 * 17 + tid];
    __syncthreads();
    for (int j = tid; j < NB * 300; j += 256) {
        int g = j / 300, c = j % 300;
        float v = me1b[c] + me2[(size_t)mt[b0 + g] * 300 + c];
        #pragma unroll
        for (int k = 0; k < 17; ++k) v += fs[g][k] * me1wT[k * 300 + c];
        mf_s[g][c] = v;
    }
    __syncthreads();
    // q = mf@wqT, m2 = relu(mf@mlwT + b): thread = output col, 2 loads feed 2*NB FMAs
    {
        float q[NB], m2[NB];
        #pragma unroll
        for (int g = 0; g < NB; ++g) { q[g] = 0.f; m2[g] = 0.f; }
        #pragma unroll 2
        for (int k = 0; k < 300; ++k) {
            float wqv = wqT[k * 256 + tid];
            float mlv = mlwT[k * 256 + tid];
            #pragma unroll
            for (int g = 0; g < NB; ++g) {
                float m = mf_s[g][k];
                q[g]  += m * wqv;
                m2[g] += m * mlv;
            }
        }
        float mb = mlb[tid];
        #pragma unroll
        for (int g = 0; g < NB; ++g) {
            q_s[g][tid] = q[g];
            metal2[(size_t)(b0 + g) * 256 + tid] = fmaxf(m2[g] + mb, 0.f);
        }
    }
    __syncthreads();
    // qk = q @ wk: thread covers cols {tid, tid+256}
    {
        float a0[NB], a1[NB];
        #pragma unroll
        for (int g = 0; g < NB; ++g) { a0[g] = 0.f; a1[g] = 0.f; }
        int c2 = tid + 256;
        bool has2 = (c2 < 300);
        #pragma unroll 2
        for (int t = 0; t < 256; ++t) {
            float w0 = wk[t * 300 + tid];
            float w1 = has2 ? wk[t * 300 + c2] : 0.f;
            #pragma unroll
            for (int g = 0; g < NB; ++g) {
                float qv = q_s[g][t];
                a0[g] += qv * w0;
                a1[g] += qv * w1;
            }
        }
        #pragma unroll
        for (int g = 0; g < NB; ++g) {
            qk[(size_t)(b0 + g) * 300 + tid] = a0[g];
            if (has2) qk[(size_t)(b0 + g) * 300 + c2] = a1[g];
        }
    }
}

// ---------------- attention pool ----------------
__global__ __launch_bounds__(320) void k_pool(const __hip_bfloat16* __restrict__ h, const float* __restrict__ qk,
                                              float* __restrict__ wpool, float* __restrict__ mean) {
    int b = blockIdx.x;
    int tid = threadIdx.x;
    int wave = tid >> 6, lane = tid & 63;
    __shared__ float qk_s[300];
    __shared__ float sc[50];
    if (tid < 300) qk_s[tid] = qk[b * 300 + tid];
    __syncthreads();
    for (int k = wave; k < 50; k += 5) {
        const __hip_bfloat16* hp = h + (long)(b * 50 + k) * LDK;
        float partial = 0.f;
        #pragma unroll
        for (int i = 0; i < 5; ++i) {
            int j = lane + i * 64;
            if (j < 300) partial += __bfloat162float(hp[j]) * qk_s[j];
        }
        #pragma unroll
        for (int s = 32; s > 0; s >>= 1) partial += __shfl_xor(partial, s, 64);
        if (lane == 0) sc[k] = partial * (1.f / 16.f);
    }
    __syncthreads();
    if (tid == 0) {
        float mx = sc[0];
        for (int k = 1; k < 50; ++k) mx = fmaxf(mx, sc[k]);
        float s = 0.f;
        for (int k = 0; k < 50; ++k) { float e = __expf(sc[k] - mx); sc[k] = e; s += e; }
        float inv = 1.f / s;
        for (int k = 0; k < 50; ++k) sc[k] *= inv;
    }
    __syncthreads();
    if (tid < 300) {
        float aw = 0.f, am = 0.f;
        for (int k = 0; k < 50; ++k) {
            float v = __bfloat162float(h[(long)(b * 50 + k) * LDK + tid]);
            aw += sc[k] * v;
            am += v;
        }
        wpool[b * 300 + tid] = aw;
        mean[b * 300 + tid]  = am * (1.f / 50.f);
    }
}

// ---------------- head (coalesced via transposed weights) ----------------
__global__ __launch_bounds__(512) void k_head(const float* __restrict__ wpool, const float* __restrict__ mean,
                                              const float* __restrict__ metal2,
                                              const float* __restrict__ wvT, const float* __restrict__ lgwT,
                                              const float* __restrict__ lgb,
                                              const float* __restrict__ ph1wT, const float* __restrict__ ph1b,
                                              const float* __restrict__ ph2w, const float* __restrict__ ph2b,
                                              float* __restrict__ out) {
    int b = blockIdx.x;
    int tid = threadIdx.x;
    __shared__ float wp_s[300], mn_s[300], f_s[256], red[512];
    if (tid < 300) { wp_s[tid] = wpool[b * 300 + tid]; mn_s[tid] = mean[b * 300 + tid]; }
    __syncthreads();
    if (tid < 256) {
        float att = 0.f, lg = 0.f;
        #pragma unroll 4
        for (int k = 0; k < 300; ++k) {
            att += wp_s[k] * wvT[k * 256 + tid];
            lg  += mn_s[k] * lgwT[k * 256 + tid];
        }
        lg = fmaxf(lg + lgb[tid], 0.f);
        f_s[tid] = fmaxf(att, 0.f) + metal2[b * 256 + tid] + lg;
    }
    __syncthreads();
    float a = ph1b[tid];
    #pragma unroll 8
    for (int k = 0; k < 256; ++k) a += f_s[k] * ph1wT[k * 512 + tid];
    float sp = fmaxf(a, 0.f) + log1pf(__expf(-fabsf(a)));   // stable softplus
    red[tid] = sp * ph2w[tid];
    __syncthreads();
    for (int s = 256; s > 0; s >>= 1) {
        if (tid < s) red[tid] += red[tid + s];
        __syncthreads();
    }
    if (tid == 0) out[b] = red[0] + ph2b[0];
}

extern "C" void kernel_launch(void* const* d_in, const int* in_sizes, int n_in,
                              void* d_out, int out_size, void* d_ws, size_t ws_size,
                              hipStream_t stream) {
    const int*   x_type   = (const int*)d_in[0];
    const float* x_feat   = (const float*)d_in[1];
    const int*   eindex   = (const int*)d_in[2];
    const float* eattr    = (const float*)d_in[3];
    const int*   mtype    = (const int*)d_in[4];
    const float* mfeat    = (const float*)d_in[5];
    const float* x_emb    = (const float*)d_in[6];
    const float* x_weight = (const float*)d_in[7];
    const float* ew1      = (const float*)d_in[8];
    const float* mlp_w    = (const float*)d_in[9];
    const float* mlp_b    = (const float*)d_in[10];
    const float* bn_g     = (const float*)d_in[11];
    const float* bn_b     = (const float*)d_in[12];
    const float* bn_rm    = (const float*)d_in[13];
    const float* bn_rv    = (const float*)d_in[14];
    const float* me1_w    = (const float*)d_in[15];
    const float* me1_b    = (const float*)d_in[16];
    const float* me2      = (const float*)d_in[17];
    const float* wq       = (const float*)d_in[18];
    const float* wk       = (const float*)d_in[19];
    const float* wv       = (const float*)d_in[20];
    const float* ml_w     = (const float*)d_in[21];
    const float* ml_b     = (const float*)d_in[22];
    const float* lg_w     = (const float*)d_in[23];
    const float* lg_b     = (const float*)d_in[24];
    const float* ph1_w    = (const float*)d_in[25];
    const float* ph1_b    = (const float*)d_in[26];
    const float* ph2_w    = (const float*)d_in[27];
    const float* ph2_b    = (const float*)d_in[28];

    char* ws = (char*)d_ws;
    size_t o = 0;
    auto alloc = [&](size_t bytes) -> void* {
        void* p = ws + o;
        o += (bytes + 255) & ~(size_t)255;
        return p;
    };
    __hip_bfloat16* h    = (__hip_bfloat16*)alloc((size_t)MPAD * LDK * 2);
    __hip_bfloat16* mh   = (__hip_bfloat16*)alloc((size_t)MPAD * LDK * 2);
    __hip_bfloat16* wb   = (__hip_bfloat16*)alloc((size_t)5 * 320 * 320 * 2);
    int*     cnt    = (int*)alloc((size_t)NNODES * 4);
    int*     offs   = (int*)alloc((size_t)(NNODES + 1) * 4);
    int*     cur    = (int*)alloc((size_t)NNODES * 4);
    int*     bsum   = (int*)alloc((size_t)64 * 4);
    EdgeRec* pack   = (EdgeRec*)alloc((size_t)NTOT * sizeof(EdgeRec));
    float*   prm    = (float*)alloc((size_t)NLAYERS * 1520 * 4);
    float*   metal2 = (float*)alloc((size_t)1000 * 256 * 4);
    float*   qk     = (float*)alloc((size_t)1000 * 300 * 4);
    float*   wpool  = (float*)alloc((size_t)1000 * 300 * 4);
    float*   meanp  = (float*)alloc((size_t)1000 * 300 * 4);
    float*   wqT    = (float*)alloc((size_t)300 * 256 * 4);
    float*   mlwT   = (float*)alloc((size_t)300 * 256 * 4);
    float*   wvT    = (float*)alloc((size_t)300 * 256 * 4);
    float*   lgwT   = (float*)alloc((size_t)300 * 256 * 4);
    float*   ph1wT  = (float*)alloc((size_t)256 * 512 * 4);
    float*   me1wT  = (float*)alloc((size_t)17 * 300 * 4);
    (void)ws_size; (void)in_sizes; (void)n_in; (void)out_size;

    hipMemsetAsync(cnt, 0, (size_t)NNODES * 4, stream);
    hipMemsetAsync(cur, 0, (size_t)NNODES * 4, stream);

    k_cvt<<<(5 * 320 * 320 + 255) / 256, 256, 0, stream>>>(mlp_w, wb);
    k_trall<<<(443372 + 255) / 256, 256, 0, stream>>>(wq, ml_w, wv, lg_w, ph1_w, me1_w,
                                                      wqT, mlwT, wvT, lgwT, ph1wT, me1wT);
    k_init<<<(NNODES * 38 + 255) / 256, 256, 0, stream>>>(x_type, x_feat, x_emb, x_weight, h);
    k_count<<<(NTOT + 255) / 256, 256, 0, stream>>>(eindex, cnt);
    k_scan1<<<NSCAN, 1024, 0, stream>>>(cnt, offs, bsum);
    k_scan2<<<1, 64, 0, stream>>>(bsum);
    k_scan3<<<NSCAN, 1024, 0, stream>>>(offs, bsum);
    k_fill<<<(NTOT + 255) / 256, 256, 0, stream>>>(eindex, eattr, offs, cur, pack);
    {
        dim3 gp(300, NLAYERS);
        k_prep<<<gp, 64, 0, stream>>>(mlp_w, ew1, mlp_b, bn_g, bn_b, bn_rm, bn_rv, prm);
    }

    for (int l = 0; l < NLAYERS; ++l) {
        dim3 g(MPAD / 128, 2);
        k_gemm<<<g, 256, 0, stream>>>(h, wb + (size_t)l * 102400, mh);
        k_aggr<<<(NNODES + 3) / 4, 256, 0, stream>>>(mh, pack, offs, prm + (size_t)l * 1520, h,
                                                     (l < NLAYERS - 1) ? 1 : 0);
    }

    k_metal<<<1000 / NB, 256, 0, stream>>>(mtype, mfeat, me1wT, me1_b, me2, wqT, wk, mlwT, ml_b, metal2, qk);
    k_pool<<<1000, 320, 0, stream>>>(h, qk, wpool, meanp);
    k_head<<<1000, 512, 0, stream>>>(wpool, meanp, metal2, wvT, lgwT, lg_b,
                                     ph1wT, ph1_b, ph2_w, ph2_b, (float*)d_out);
}

// Round 7
// 662.303 us; speedup vs baseline: 2.5188x; 1.0981x over previous
//
#include <hip/hip_runtime.h>
#include <hip/hip_bf16.h>
#include <math.h>

#define NNODES  50000
#define NEDGES  200000
#define NTOT    250000      // E + N self loops
#define EMB     300
#define LDK     320         // padded K stride (bf16 h / mh / weights)
#define MPAD    50048       // 391 * 128 (GEMM M padding)
#define NLAYERS 5
#define NSCAN   49          // ceil(NNODES / 1024)

struct EdgeRec { int r; float c0, c1; };

typedef __attribute__((ext_vector_type(8))) short short8;
typedef __attribute__((ext_vector_type(4))) short short4v;
typedef __attribute__((ext_vector_type(4))) float floatx4;

__device__ inline void gll16(const void* g, void* s) {
    __builtin_amdgcn_global_load_lds((const __attribute__((address_space(1))) unsigned*)g,
                                     (__attribute__((address_space(3))) unsigned*)s, 16, 0, 0);
}

// ---------------- merged transposes for readout weights (head path only) ----------------
__global__ void k_trall(const float* __restrict__ wv, const float* __restrict__ lg_w,
                        const float* __restrict__ ph1_w, const float* __restrict__ me1_w,
                        float* __restrict__ wvT, float* __restrict__ lgwT,
                        float* __restrict__ ph1wT, float* __restrict__ me1wT) {
    int idx = blockIdx.x * 256 + threadIdx.x;
    if (idx < 76800) { int r = idx / 300, c = idx % 300; wvT[c * 256 + r] = wv[idx]; return; }
    idx -= 76800;
    if (idx < 76800) { int r = idx / 300, c = idx % 300; lgwT[c * 256 + r] = lg_w[idx]; return; }
    idx -= 76800;
    if (idx < 131072) { int r = idx / 256, c = idx % 256; ph1wT[c * 512 + r] = ph1_w[idx]; return; }
    idx -= 131072;
    if (idx < 5100) { int r = idx / 17, c = idx % 17; me1wT[c * 300 + r] = me1_w[idx]; }
}

// ---------------- weight convert: wb[l][320][320] = bf16(mlp_w[l][300][300]) zero-padded ----------------
__global__ void k_cvt(const float* __restrict__ w, __hip_bfloat16* __restrict__ wb) {
    int idx = blockIdx.x * 256 + threadIdx.x;
    if (idx >= 5 * 320 * 320) return;
    int l = idx / 102400, r = idx % 102400, n = r / 320, k = r % 320;
    float v = (n < 300 && k < 300) ? w[l * 90000 + n * 300 + k] : 0.f;
    wb[idx] = __float2bfloat16(v);
}

// ---------------- metal-path weight packs: wcat[512][320] = [wq; ml_w], wkTb[320][256] = wk^T ----------------
__global__ void k_cvt2(const float* __restrict__ wq, const float* __restrict__ ml_w,
                       const float* __restrict__ wk,
                       __hip_bfloat16* __restrict__ wcat, __hip_bfloat16* __restrict__ wkTb) {
    int idx = blockIdx.x * 256 + threadIdx.x;
    if (idx < 512 * 320) {
        int r = idx / 320, k = idx % 320;
        float v = 0.f;
        if (k < 300) v = (r < 256) ? wq[r * 300 + k] : ml_w[(r - 256) * 300 + k];
        wcat[idx] = __float2bfloat16(v);
        return;
    }
    idx -= 512 * 320;
    if (idx < 320 * 256) {
        int c = idx / 256, j = idx % 256;
        float v = (c < 300) ? wk[j * 300 + c] : 0.f;
        wkTb[idx] = __float2bfloat16(v);
    }
}

// ---------------- mf = me1b + me2[mt] + mfeat @ me1wT, bf16 [1024,320] (pads pre-zeroed) ----------------
__global__ __launch_bounds__(256) void k_mf(const int* __restrict__ mt, const float* __restrict__ mfeat,
                                            const float* __restrict__ me1wT, const float* __restrict__ me1b,
                                            const float* __restrict__ me2,
                                            __hip_bfloat16* __restrict__ mfb) {
    int idx = blockIdx.x * 256 + threadIdx.x;
    if (idx >= 1000 * 300) return;
    int g = idx / 300, c = idx % 300;
    float v = me1b[c] + me2[(size_t)mt[g] * 300 + c];
    #pragma unroll
    for (int k = 0; k < 17; ++k) v += mfeat[g * 17 + k] * me1wT[k * 300 + c];
    mfb[(size_t)g * 320 + c] = __float2bfloat16(v);
}

// ---------------- generic 128x64 MFMA GEMM for metal path ----------------
// mode 0: A=mfb[1024,320] B=wcat[512,320] -> cols<256: qb bf16; cols>=256: metal2=relu(+mlb)
// mode 1: A=qb[1024,256]  B=wkTb[320,256] -> qk fp32 [1000,320]
__global__ __launch_bounds__(256) void k_mm(const __hip_bfloat16* __restrict__ A, int lda,
                                            const __hip_bfloat16* __restrict__ B, int ldb,
                                            int K, int mode,
                                            const float* __restrict__ mlb,
                                            __hip_bfloat16* __restrict__ qb,
                                            float* __restrict__ metal2,
                                            float* __restrict__ qkout) {
    __shared__ __hip_bfloat16 As[128 * 32];
    __shared__ __hip_bfloat16 Bs[64 * 32];
    int tid = threadIdx.x, lane = tid & 63, w = tid >> 6;
    int row0 = blockIdx.x * 128, col0 = blockIdx.y * 64;

    floatx4 acc[2][4];
    #pragma unroll
    for (int i = 0; i < 2; ++i)
        #pragma unroll
        for (int j = 0; j < 4; ++j) acc[i][j] = (floatx4){0.f, 0.f, 0.f, 0.f};

    const __hip_bfloat16* ga0 = A + (size_t)(row0 + w * 32 + (lane >> 2)) * lda + (lane & 3) * 8;
    const __hip_bfloat16* ga1 = ga0 + (size_t)16 * lda;
    const __hip_bfloat16* gb  = B + (size_t)(col0 + w * 16 + (lane >> 2)) * ldb + (lane & 3) * 8;
    __hip_bfloat16* sa0 = &As[(w * 32) * 32];
    __hip_bfloat16* sa1 = &As[(w * 32 + 16) * 32];
    __hip_bfloat16* sb  = &Bs[(w * 16) * 32];

    int m15 = lane & 15, kof = (lane >> 4) * 8;

    for (int k0 = 0; k0 < K; k0 += 32) {
        __syncthreads();
        gll16(ga0 + k0, sa0);
        gll16(ga1 + k0, sa1);
        gll16(gb  + k0, sb);
        __syncthreads();

        short8 a[2], b[4];
        a[0] = *(const short8*)&As[(w * 32 +      m15) * 32 + kof];
        a[1] = *(const short8*)&As[(w * 32 + 16 + m15) * 32 + kof];
        #pragma unroll
        for (int nt = 0; nt < 4; ++nt)
            b[nt] = *(const short8*)&Bs[(nt * 16 + m15) * 32 + kof];

        #pragma unroll
        for (int mt = 0; mt < 2; ++mt)
            #pragma unroll
            for (int nt = 0; nt < 4; ++nt)
                acc[mt][nt] = __builtin_amdgcn_mfma_f32_16x16x32_bf16(a[mt], b[nt], acc[mt][nt], 0, 0, 0);
    }

    int rbase = row0 + w * 32 + (lane >> 4) * 4;
    #pragma unroll
    for (int mt = 0; mt < 2; ++mt)
        #pragma unroll
        for (int i = 0; i < 4; ++i) {
            int gr = rbase + mt * 16 + i;
            #pragma unroll
            for (int nt = 0; nt < 4; ++nt) {
                int gc = col0 + nt * 16 + m15;
                float v = acc[mt][nt][i];
                if (mode == 0) {
                    if (gc < 256) qb[(size_t)gr * 256 + gc] = __float2bfloat16(v);
                    else if (gr < 1000) metal2[(size_t)gr * 256 + (gc - 256)] = fmaxf(v + mlb[gc - 256], 0.f);
                } else {
                    if (gc < 300 && gr < 1000) qkout[(size_t)gr * 320 + gc] = v;
                }
            }
        }
}

// ---------------- node init: h = bf16(x_emb[x_type] + x_feat @ x_weight), 8 cols/thread ----------------
__global__ __launch_bounds__(256) void k_init(const int* __restrict__ xt,
                                              const float* __restrict__ xf,
                                              const float* __restrict__ xemb,
                                              const float* __restrict__ xw,
                                              __hip_bfloat16* __restrict__ h) {
    int gid = blockIdx.x * 256 + threadIdx.x;
    if (gid >= NNODES * 38) return;
    int n = gid / 38, c = (gid % 38) * 8;     // c in {0,8,...,296}
    bool full = (c <= 292);
    const float* er = xemb + (size_t)xt[n] * 300 + c;
    float v[8];
    float4 e0 = *(const float4*)er;
    v[0] = e0.x; v[1] = e0.y; v[2] = e0.z; v[3] = e0.w;
    if (full) { float4 e1 = *(const float4*)(er + 4); v[4] = e1.x; v[5] = e1.y; v[6] = e1.z; v[7] = e1.w; }
    else      { v[4] = v[5] = v[6] = v[7] = 0.f; }
    float fs[16];
    const float4* xf4 = (const float4*)(xf + n * 16);
    #pragma unroll
    for (int q = 0; q < 4; ++q) {
        float4 t = xf4[q];
        fs[4 * q] = t.x; fs[4 * q + 1] = t.y; fs[4 * q + 2] = t.z; fs[4 * q + 3] = t.w;
    }
    #pragma unroll
    for (int k = 0; k < 16; ++k) {
        const float* wr = xw + k * 300 + c;
        float4 w0 = *(const float4*)wr;
        v[0] += fs[k] * w0.x; v[1] += fs[k] * w0.y; v[2] += fs[k] * w0.z; v[3] += fs[k] * w0.w;
        if (full) {
            float4 w1 = *(const float4*)(wr + 4);
            v[4] += fs[k] * w1.x; v[5] += fs[k] * w1.y; v[6] += fs[k] * w1.z; v[7] += fs[k] * w1.w;
        }
    }
    alignas(16) __hip_bfloat16 ob[8];
    #pragma unroll
    for (int i = 0; i < 8; ++i) ob[i] = __float2bfloat16(v[i]);
    __hip_bfloat16* hp = h + (size_t)n * LDK + c;
    if (full) *(short8*)hp  = *(const short8*)ob;
    else      *(short4v*)hp = *(const short4v*)ob;
}

// ---------------- CSR build ----------------
__global__ void k_count(const int* __restrict__ ei, int* __restrict__ cnt) {
    int e = blockIdx.x * blockDim.x + threadIdx.x;
    if (e >= NTOT) return;
    int c = (e < NEDGES) ? ei[NEDGES + e] : (e - NEDGES);
    atomicAdd(&cnt[c], 1);
}

__global__ __launch_bounds__(1024) void k_scan1(const int* __restrict__ cnt, int* __restrict__ off,
                                                int* __restrict__ bsum) {
    int tid = threadIdx.x;
    int gid = blockIdx.x * 1024 + tid;
    int lane = tid & 63, wv = tid >> 6;
    int v = (gid < NNODES) ? cnt[gid] : 0;
    int x = v;
    #pragma unroll
    for (int s = 1; s < 64; s <<= 1) {
        int t = __shfl_up(x, s, 64);
        if (lane >= s) x += t;
    }
    __shared__ int wsum[16];
    if (lane == 63) wsum[wv] = x;
    __syncthreads();
    if (wv == 0) {
        int w = (lane < 16) ? wsum[lane] : 0;
        #pragma unroll
        for (int s = 1; s < 16; s <<= 1) {
            int t = __shfl_up(w, s, 64);
            if (lane >= s) w += t;
        }
        if (lane < 16) wsum[lane] = w;
    }
    __syncthreads();
    int base = (wv > 0) ? wsum[wv - 1] : 0;
    int incl = x + base;
    if (gid < NNODES) off[gid] = incl - v;
    if (tid == 1023) bsum[blockIdx.x] = incl;
}

__global__ __launch_bounds__(64) void k_scan2(int* __restrict__ bsum) {
    int lane = threadIdx.x;
    int v = (lane < NSCAN) ? bsum[lane] : 0;
    int x = v;
    #pragma unroll
    for (int s = 1; s < 64; s <<= 1) {
        int t = __shfl_up(x, s, 64);
        if (lane >= s) x += t;
    }
    if (lane < NSCAN) bsum[lane] = x - v;
}

__global__ __launch_bounds__(1024) void k_scan3(int* __restrict__ off, const int* __restrict__ bsum) {
    int gid = blockIdx.x * 1024 + threadIdx.x;
    if (gid < NNODES) off[gid] += bsum[blockIdx.x];
    if (gid == 0) off[NNODES] = NTOT;
}

__global__ void k_fill(const int* __restrict__ ei, const float* __restrict__ ea,
                       const int* __restrict__ off, int* __restrict__ cur,
                       EdgeRec* __restrict__ pack) {
    int e = blockIdx.x * blockDim.x + threadIdx.x;
    if (e >= NTOT) return;
    int r, c; float c0, c1;
    if (e < NEDGES) { r = ei[e]; c = ei[NEDGES + e]; c0 = ea[2 * e]; c1 = ea[2 * e + 1]; }
    else            { r = c = e - NEDGES; c0 = 0.f; c1 = 4.f; }
    int p = atomicAdd(&cur[c], 1);
    EdgeRec rec; rec.r = r; rec.c0 = c0; rec.c1 = c1;
    pack[off[c] + p] = rec;
}

// ---------------- per-layer precompute, all layers in one launch ----------------
__global__ __launch_bounds__(64) void k_prep(const float* __restrict__ mlp_w, const float* __restrict__ ew1,
                                             const float* __restrict__ mlp_b, const float* __restrict__ bn_g,
                                             const float* __restrict__ bn_b, const float* __restrict__ bn_rm,
                                             const float* __restrict__ bn_rv, float* __restrict__ prm) {
    int j = blockIdx.x, l = blockIdx.y;
    int lane = threadIdx.x;
    const float* W  = mlp_w + (size_t)l * 90000 + (size_t)j * 300;
    const float* ew = ew1 + l * 600;
    float a0 = 0.f, a1 = 0.f;
    #pragma unroll
    for (int i = 0; i < 5; ++i) {
        int k = lane + i * 64;
        if (k < 300) {
            float w = W[k];
            a0 += w * ew[k];
            a1 += w * ew[300 + k];
        }
    }
    #pragma unroll
    for (int s = 32; s > 0; s >>= 1) { a0 += __shfl_xor(a0, s, 64); a1 += __shfl_xor(a1, s, 64); }
    if (lane == 0) {
        float* p = prm + l * 1520;
        p[j] = a0;
        p[304 + j] = a1;
        p[608 + j] = mlp_b[l * 300 + j];
        float sc = bn_g[l * 300 + j] * rsqrtf(bn_rv[l * 300 + j] + 1e-5f);
        p[912 + j] = sc;
        p[1216 + j] = bn_b[l * 300 + j] - bn_rm[l * 300 + j] * sc;
    }
}

// ---------------- MFMA GEMM (layers): C[M,320] = A[M,320] @ B[320,320]^T, 128x160 block ----------------
__global__ __launch_bounds__(256) void k_gemm(const __hip_bfloat16* __restrict__ A,
                                              const __hip_bfloat16* __restrict__ B,
                                              __hip_bfloat16* __restrict__ C) {
    __shared__ __hip_bfloat16 As[128 * 32];
    __shared__ __hip_bfloat16 Bs[160 * 32];
    int tid = threadIdx.x;
    int lane = tid & 63, w = tid >> 6;
    int row0 = blockIdx.x * 128, col0 = blockIdx.y * 160;

    floatx4 acc[2][10];
    #pragma unroll
    for (int i = 0; i < 2; ++i)
        #pragma unroll
        for (int j = 0; j < 10; ++j) acc[i][j] = (floatx4){0.f, 0.f, 0.f, 0.f};

    const __hip_bfloat16* ga0 = A + (size_t)(row0 + w * 32 + (lane >> 2)) * LDK + (lane & 3) * 8;
    const __hip_bfloat16* ga1 = ga0 + (size_t)16 * LDK;
    __hip_bfloat16* sa0 = &As[(w * 32) * 32];
    __hip_bfloat16* sa1 = &As[(w * 32 + 16) * 32];
    int brow0 = (w < 2) ? w * 48 : 96 + (w - 2) * 32;
    int nb = (w < 2) ? 3 : 2;
    const __hip_bfloat16* gb = B + (size_t)(col0 + brow0 + (lane >> 2)) * LDK + (lane & 3) * 8;
    __hip_bfloat16* sb = &Bs[brow0 * 32];

    int m15 = lane & 15, kof = (lane >> 4) * 8;

    for (int k0 = 0; k0 < LDK; k0 += 32) {
        __syncthreads();
        gll16(ga0 + k0, sa0);
        gll16(ga1 + k0, sa1);
        for (int i = 0; i < nb; ++i)
            gll16(gb + (size_t)i * 16 * LDK + k0, sb + i * 16 * 32);
        __syncthreads();

        short8 a[2], b[10];
        a[0] = *(const short8*)&As[(w * 32 +      m15) * 32 + kof];
        a[1] = *(const short8*)&As[(w * 32 + 16 + m15) * 32 + kof];
        #pragma unroll
        for (int nt = 0; nt < 10; ++nt)
            b[nt] = *(const short8*)&Bs[(nt * 16 + m15) * 32 + kof];

        #pragma unroll
        for (int mt = 0; mt < 2; ++mt)
            #pragma unroll
            for (int nt = 0; nt < 10; ++nt)
                acc[mt][nt] = __builtin_amdgcn_mfma_f32_16x16x32_bf16(a[mt], b[nt], acc[mt][nt], 0, 0, 0);
    }

    int rbase = row0 + w * 32 + (lane >> 4) * 4;
    #pragma unroll
    for (int mt = 0; mt < 2; ++mt)
        #pragma unroll
        for (int i = 0; i < 4; ++i) {
            long gr = rbase + mt * 16 + i;
            #pragma unroll
            for (int nt = 0; nt < 10; ++nt)
                C[gr * LDK + col0 + nt * 16 + m15] = __float2bfloat16(acc[mt][nt][i]);
        }
}

// ---------------- aggregate: wave/node, 2-edge unroll ----------------
__global__ __launch_bounds__(256) void k_aggr(const __hip_bfloat16* __restrict__ mh,
                                              const EdgeRec* __restrict__ pack,
                                              const int* __restrict__ off, const float* __restrict__ prm,
                                              __hip_bfloat16* __restrict__ h, int do_relu) {
    int wave = threadIdx.x >> 6;
    int lane = threadIdx.x & 63;
    int n = blockIdx.x * 4 + wave;
    if (n >= NNODES) return;
    float u0[3][2], u1[3][2], bv[3][2], sc[3][2], sh[3][2], acc[3][2];
    #pragma unroll
    for (int i = 0; i < 3; ++i) {
        int j = 2 * lane + 128 * i;
        #pragma unroll
        for (int t = 0; t < 2; ++t) {
            bool ok = (j + t) < 300;
            u0[i][t] = ok ? prm[j + t]        : 0.f;
            u1[i][t] = ok ? prm[304 + j + t]  : 0.f;
            bv[i][t] = ok ? prm[608 + j + t]  : 0.f;
            sc[i][t] = ok ? prm[912 + j + t]  : 0.f;
            sh[i][t] = ok ? prm[1216 + j + t] : 0.f;
            acc[i][t] = 0.f;
        }
    }
    int p0 = off[n], p1 = off[n + 1];
    int p = p0;
    for (; p + 1 < p1; p += 2) {
        EdgeRec e0 = pack[p], e1 = pack[p + 1];
        const __hip_bfloat16* b0 = mh + (size_t)e0.r * LDK;
        const __hip_bfloat16* b1 = mh + (size_t)e1.r * LDK;
        __hip_bfloat162 hv0[3], hv1[3];
        #pragma unroll
        for (int i = 0; i < 3; ++i) {
            int j = 2 * lane + 128 * i;
            if (j < 300) {
                hv0[i] = *(const __hip_bfloat162*)&b0[j];
                hv1[i] = *(const __hip_bfloat162*)&b1[j];
            }
        }
        #pragma unroll
        for (int i = 0; i < 3; ++i) {
            int j = 2 * lane + 128 * i;
            if (j < 300) {
                acc[i][0] += fmaxf(__bfloat162float(hv0[i].x) + e0.c0 * u0[i][0] + e0.c1 * u1[i][0] + bv[i][0], 0.f);
                acc[i][1] += fmaxf(__bfloat162float(hv0[i].y) + e0.c0 * u0[i][1] + e0.c1 * u1[i][1] + bv[i][1], 0.f);
                acc[i][0] += fmaxf(__bfloat162float(hv1[i].x) + e1.c0 * u0[i][0] + e1.c1 * u1[i][0] + bv[i][0], 0.f);
                acc[i][1] += fmaxf(__bfloat162float(hv1[i].y) + e1.c0 * u0[i][1] + e1.c1 * u1[i][1] + bv[i][1], 0.f);
            }
        }
    }
    if (p < p1) {
        EdgeRec e0 = pack[p];
        const __hip_bfloat16* b0 = mh + (size_t)e0.r * LDK;
        #pragma unroll
        for (int i = 0; i < 3; ++i) {
            int j = 2 * lane + 128 * i;
            if (j < 300) {
                __hip_bfloat162 hv = *(const __hip_bfloat162*)&b0[j];
                acc[i][0] += fmaxf(__bfloat162float(hv.x) + e0.c0 * u0[i][0] + e0.c1 * u1[i][0] + bv[i][0], 0.f);
                acc[i][1] += fmaxf(__bfloat162float(hv.y) + e0.c0 * u0[i][1] + e0.c1 * u1[i][1] + bv[i][1], 0.f);
            }
        }
    }
    #pragma unroll
    for (int i = 0; i < 3; ++i) {
        int j = 2 * lane + 128 * i;
        if (j < 300) {
            float v0 = acc[i][0] * sc[i][0] + sh[i][0];
            float v1 = acc[i][1] * sc[i][1] + sh[i][1];
            if (do_relu) { v0 = fmaxf(v0, 0.f); v1 = fmaxf(v1, 0.f); }
            __hip_bfloat162 o;
            o.x = __float2bfloat16(v0);
            o.y = __float2bfloat16(v1);
            *(__hip_bfloat162*)&h[(size_t)n * LDK + j] = o;
        }
    }
}

// ---------------- attention pool (qk stride 320 now) ----------------
__global__ __launch_bounds__(320) void k_pool(const __hip_bfloat16* __restrict__ h, const float* __restrict__ qk,
                                              float* __restrict__ wpool, float* __restrict__ mean) {
    int b = blockIdx.x;
    int tid = threadIdx.x;
    int wave = tid >> 6, lane = tid & 63;
    __shared__ float qk_s[300];
    __shared__ float sc[50];
    if (tid < 300) qk_s[tid] = qk[(size_t)b * 320 + tid];
    __syncthreads();
    for (int k = wave; k < 50; k += 5) {
        const __hip_bfloat16* hp = h + (long)(b * 50 + k) * LDK;
        float partial = 0.f;
        #pragma unroll
        for (int i = 0; i < 5; ++i) {
            int j = lane + i * 64;
            if (j < 300) partial += __bfloat162float(hp[j]) * qk_s[j];
        }
        #pragma unroll
        for (int s = 32; s > 0; s >>= 1) partial += __shfl_xor(partial, s, 64);
        if (lane == 0) sc[k] = partial * (1.f / 16.f);
    }
    __syncthreads();
    if (tid == 0) {
        float mx = sc[0];
        for (int k = 1; k < 50; ++k) mx = fmaxf(mx, sc[k]);
        float s = 0.f;
        for (int k = 0; k < 50; ++k) { float e = __expf(sc[k] - mx); sc[k] = e; s += e; }
        float inv = 1.f / s;
        for (int k = 0; k < 50; ++k) sc[k] *= inv;
    }
    __syncthreads();
    if (tid < 300) {
        float aw = 0.f, am = 0.f;
        for (int k = 0; k < 50; ++k) {
            float v = __bfloat162float(h[(long)(b * 50 + k) * LDK + tid]);
            aw += sc[k] * v;
            am += v;
        }
        wpool[b * 300 + tid] = aw;
        mean[b * 300 + tid]  = am * (1.f / 50.f);
    }
}

// ---------------- head (coalesced via transposed weights) ----------------
__global__ __launch_bounds__(512) void k_head(const float* __restrict__ wpool, const float* __restrict__ mean,
                                              const float* __restrict__ metal2,
                                              const float* __restrict__ wvT, const float* __restrict__ lgwT,
                                              const float* __restrict__ lgb,
                                              const float* __restrict__ ph1wT, const float* __restrict__ ph1b,
                                              const float* __restrict__ ph2w, const float* __restrict__ ph2b,
                                              float* __restrict__ out) {
    int b = blockIdx.x;
    int tid = threadIdx.x;
    __shared__ float wp_s[300], mn_s[300], f_s[256], red[512];
    if (tid < 300) { wp_s[tid] = wpool[b * 300 + tid]; mn_s[tid] = mean[b * 300 + tid]; }
    __syncthreads();
    if (tid < 256) {
        float att = 0.f, lg = 0.f;
        #pragma unroll 4
        for (int k = 0; k < 300; ++k) {
            att += wp_s[k] * wvT[k * 256 + tid];
            lg  += mn_s[k] * lgwT[k * 256 + tid];
        }
        lg = fmaxf(lg + lgb[tid], 0.f);
        f_s[tid] = fmaxf(att, 0.f) + metal2[b * 256 + tid] + lg;
    }
    __syncthreads();
    float a = ph1b[tid];
    #pragma unroll 8
    for (int k = 0; k < 256; ++k) a += f_s[k] * ph1wT[k * 512 + tid];
    float sp = fmaxf(a, 0.f) + log1pf(__expf(-fabsf(a)));   // stable softplus
    red[tid] = sp * ph2w[tid];
    __syncthreads();
    for (int s = 256; s > 0; s >>= 1) {
        if (tid < s) red[tid] += red[tid + s];
        __syncthreads();
    }
    if (tid == 0) out[b] = red[0] + ph2b[0];
}

extern "C" void kernel_launch(void* const* d_in, const int* in_sizes, int n_in,
                              void* d_out, int out_size, void* d_ws, size_t ws_size,
                              hipStream_t stream) {
    const int*   x_type   = (const int*)d_in[0];
    const float* x_feat   = (const float*)d_in[1];
    const int*   eindex   = (const int*)d_in[2];
    const float* eattr    = (const float*)d_in[3];
    const int*   mtype    = (const int*)d_in[4];
    const float* mfeat    = (const float*)d_in[5];
    const float* x_emb    = (const float*)d_in[6];
    const float* x_weight = (const float*)d_in[7];
    const float* ew1      = (const float*)d_in[8];
    const float* mlp_w    = (const float*)d_in[9];
    const float* mlp_b    = (const float*)d_in[10];
    const float* bn_g     = (const float*)d_in[11];
    const float* bn_b     = (const float*)d_in[12];
    const float* bn_rm    = (const float*)d_in[13];
    const float* bn_rv    = (const float*)d_in[14];
    const float* me1_w    = (const float*)d_in[15];
    const float* me1_b    = (const float*)d_in[16];
    const float* me2      = (const float*)d_in[17];
    const float* wq       = (const float*)d_in[18];
    const float* wk       = (const float*)d_in[19];
    const float* wv       = (const float*)d_in[20];
    const float* ml_w     = (const float*)d_in[21];
    const float* ml_b     = (const float*)d_in[22];
    const float* lg_w     = (const float*)d_in[23];
    const float* lg_b     = (const float*)d_in[24];
    const float* ph1_w    = (const float*)d_in[25];
    const float* ph1_b    = (const float*)d_in[26];
    const float* ph2_w    = (const float*)d_in[27];
    const float* ph2_b    = (const float*)d_in[28];

    char* ws = (char*)d_ws;
    size_t o = 0;
    auto alloc = [&](size_t bytes) -> void* {
        void* p = ws + o;
        o += (bytes + 255) & ~(size_t)255;
        return p;
    };
    __hip_bfloat16* h    = (__hip_bfloat16*)alloc((size_t)MPAD * LDK * 2);
    __hip_bfloat16* mh   = (__hip_bfloat16*)alloc((size_t)MPAD * LDK * 2);
    __hip_bfloat16* wb   = (__hip_bfloat16*)alloc((size_t)5 * 320 * 320 * 2);
    int*     cnt    = (int*)alloc((size_t)NNODES * 4);
    int*     offs   = (int*)alloc((size_t)(NNODES + 1) * 4);
    int*     cur    = (int*)alloc((size_t)NNODES * 4);
    int*     bsum   = (int*)alloc((size_t)64 * 4);
    EdgeRec* pack   = (EdgeRec*)alloc((size_t)NTOT * sizeof(EdgeRec));
    float*   prm    = (float*)alloc((size_t)NLAYERS * 1520 * 4);
    float*   metal2 = (float*)alloc((size_t)1000 * 256 * 4);
    float*   qk     = (float*)alloc((size_t)1024 * 320 * 4);
    float*   wpool  = (float*)alloc((size_t)1000 * 300 * 4);
    float*   meanp  = (float*)alloc((size_t)1000 * 300 * 4);
    float*   wvT    = (float*)alloc((size_t)300 * 256 * 4);
    float*   lgwT   = (float*)alloc((size_t)300 * 256 * 4);
    float*   ph1wT  = (float*)alloc((size_t)256 * 512 * 4);
    float*   me1wT  = (float*)alloc((size_t)17 * 300 * 4);
    __hip_bfloat16* mfb  = (__hip_bfloat16*)alloc((size_t)1024 * 320 * 2);
    __hip_bfloat16* wcat = (__hip_bfloat16*)alloc((size_t)512 * 320 * 2);
    __hip_bfloat16* wkTb = (__hip_bfloat16*)alloc((size_t)320 * 256 * 2);
    __hip_bfloat16* qb   = (__hip_bfloat16*)alloc((size_t)1024 * 256 * 2);
    (void)ws_size; (void)in_sizes; (void)n_in; (void)out_size;

    hipMemsetAsync(cnt, 0, (size_t)NNODES * 4, stream);
    hipMemsetAsync(cur, 0, (size_t)NNODES * 4, stream);
    hipMemsetAsync(mfb, 0, (size_t)1024 * 320 * 2, stream);

    k_cvt<<<(5 * 320 * 320 + 255) / 256, 256, 0, stream>>>(mlp_w, wb);
    k_cvt2<<<(512 * 320 + 320 * 256 + 255) / 256, 256, 0, stream>>>(wq, ml_w, wk, wcat, wkTb);
    k_trall<<<(289772 + 255) / 256, 256, 0, stream>>>(wv, lg_w, ph1_w, me1_w, wvT, lgwT, ph1wT, me1wT);
    k_init<<<(NNODES * 38 + 255) / 256, 256, 0, stream>>>(x_type, x_feat, x_emb, x_weight, h);
    k_count<<<(NTOT + 255) / 256, 256, 0, stream>>>(eindex, cnt);
    k_scan1<<<NSCAN, 1024, 0, stream>>>(cnt, offs, bsum);
    k_scan2<<<1, 64, 0, stream>>>(bsum);
    k_scan3<<<NSCAN, 1024, 0, stream>>>(offs, bsum);
    k_fill<<<(NTOT + 255) / 256, 256, 0, stream>>>(eindex, eattr, offs, cur, pack);
    {
        dim3 gp(300, NLAYERS);
        k_prep<<<gp, 64, 0, stream>>>(mlp_w, ew1, mlp_b, bn_g, bn_b, bn_rm, bn_rv, prm);
    }
    // metal path: mf -> {q, metal2} -> qk  (batched MFMA GEMMs)
    k_mf<<<(1000 * 300 + 255) / 256, 256, 0, stream>>>(mtype, mfeat, me1wT, me1_b, me2, mfb);
    {
        dim3 g1(8, 8);   // M=1024, N=512, K=320
        k_mm<<<g1, 256, 0, stream>>>(mfb, 320, wcat, 320, 320, 0, ml_b, qb, metal2, qk);
        dim3 g2(8, 5);   // M=1024, N=320, K=256
        k_mm<<<g2, 256, 0, stream>>>(qb, 256, wkTb, 256, 256, 1, ml_b, qb, metal2, qk);
    }

    for (int l = 0; l < NLAYERS; ++l) {
        dim3 g(MPAD / 128, 2);
        k_gemm<<<g, 256, 0, stream>>>(h, wb + (size_t)l * 102400, mh);
        k_aggr<<<(NNODES + 3) / 4, 256, 0, stream>>>(mh, pack, offs, prm + (size_t)l * 1520, h,
                                                     (l < NLAYERS - 1) ? 1 : 0);
    }

    k_pool<<<1000, 320, 0, stream>>>(h, qk, wpool, meanp);
    k_head<<<1000, 512, 0, stream>>>(wpool, meanp, metal2, wvT, lgwT, lg_b,
                                     ph1wT, ph1_b, ph2_w, ph2_b, (float*)d_out);
}